// Round 2
// baseline (464.532 us; speedup 1.0000x reference)
//
#include <hip/hip_runtime.h>

typedef __attribute__((ext_vector_type(8))) _Float16 half8;
typedef __attribute__((ext_vector_type(4))) _Float16 half4;
typedef __attribute__((ext_vector_type(4))) float    floatx4;

#define GLD16(g, l)                                                            \
  __builtin_amdgcn_global_load_lds(                                            \
      (const __attribute__((address_space(1))) void*)(g),                      \
      (__attribute__((address_space(3))) void*)(l), 16, 0, 0)

__device__ __forceinline__ void cvt8(const float* __restrict__ in,
                                     _Float16* __restrict__ out, int i) {
  const float4* p = (const float4*)in + (size_t)i * 2;
  float4 a = p[0], b = p[1];
  half8 h;
  h[0] = (_Float16)a.x; h[1] = (_Float16)a.y; h[2] = (_Float16)a.z; h[3] = (_Float16)a.w;
  h[4] = (_Float16)b.x; h[5] = (_Float16)b.y; h[6] = (_Float16)b.z; h[7] = (_Float16)b.w;
  *(half8*)(out + (size_t)i * 8) = h;
}

// ---- prepA (fused): cvt emb (4096 blk) + cvt Wq (8192 blk) + prep_kv (8192) -
__global__ __launch_bounds__(256) void prepA(const float* __restrict__ emb,
                                             const float* __restrict__ Wq,
                                             const float* __restrict__ keys,
                                             const float* __restrict__ values,
                                             _Float16* __restrict__ embH,
                                             _Float16* __restrict__ WqH,
                                             _Float16* __restrict__ Kh,
                                             _Float16* __restrict__ Vt) {
  const int bid = blockIdx.x, t = threadIdx.x;
  if (bid < 4096) {
    cvt8(emb, embH, bid * 256 + t);
  } else if (bid < 12288) {
    cvt8(Wq, WqH, (bid - 4096) * 256 + t);
  } else {
    const int tid = (bid - 12288) * 256 + t;  // < 2M
    {
      int v = tid & 63, n = (tid >> 6) & 511, h = (tid >> 15) & 15, b = tid >> 19;
      Kh[tid] = (_Float16)keys[((size_t)(b * 512 + n)) * 1024 + v * 16 + h];
    }
    {
      int n = tid & 511, v = (tid >> 9) & 63, h = (tid >> 15) & 15, b = tid >> 19;
      Vt[tid] = (_Float16)values[((size_t)(b * 512 + n)) * 1024 + v * 16 + h];
    }
  }
}

// ---------------- GEMM_BT split-K, BK=64 (known-good 128x128 structure) ------
// C[m,n] = sum_k A[m,k]*B[n,k]. M=2048, N=4096, K=4096 split in 2 (blockIdx.z),
// 32 iters of BK=64. 128x128 tile, 4 waves (2x2 of 64x64), 32 KB LDS.
// XOR slot swizzle (chunk c stored at cslot c^(row&7)) kills bank aliasing of
// the 128B row stride; applied on the global SOURCE address (global_load_lds
// dest must stay lane-linear).
// MODE 1 (gemm1): z=0 -> H0 f16 linear, z=1 -> H1 f16 linear (no bias)
// MODE 0 (gemm2): z=0 -> Cf f32 linear + bias[col], z=1 -> H1 f16 linear
template <int MODE>
__global__ __launch_bounds__(256, 3) void gemm_bt(const _Float16* __restrict__ A,
                                                  const _Float16* __restrict__ Bw,
                                                  const float* __restrict__ bias,
                                                  float* __restrict__ Cf,
                                                  _Float16* __restrict__ H0,
                                                  _Float16* __restrict__ H1) {
  const int K = 4096;
  __shared__ _Float16 lA[128 * 64];
  __shared__ _Float16 lB[128 * 64];
  const int t = threadIdx.x, lane = t & 63, w = t >> 6;
  const int m0 = blockIdx.y * 128, n0 = blockIdx.x * 128;
  const int kb = blockIdx.z * 2048;
  const int wm = (w >> 1) * 64, wn = (w & 1) * 64;
  const int fr = lane & 15, fq = lane >> 4;

  floatx4 acc[4][4];
#pragma unroll
  for (int i = 0; i < 4; i++)
#pragma unroll
    for (int j = 0; j < 4; j++) acc[i][j] = (floatx4)(0.f);

  const int srow = t >> 3;
  const int sch = (t & 7) ^ (srow & 7);
  const _Float16* gA = A + (size_t)(m0 + srow) * K + kb + sch * 8;
  const _Float16* gB = Bw + (size_t)(n0 + srow) * K + kb + sch * 8;
  _Float16* dA = &lA[t * 8];
  _Float16* dB = &lB[t * 8];

  for (int k0 = 0; k0 < 2048; k0 += 64) {
    GLD16(gA, dA);
    GLD16(gA + (size_t)32 * K, dA + 2048);
    GLD16(gA + (size_t)64 * K, dA + 4096);
    GLD16(gA + (size_t)96 * K, dA + 6144);
    GLD16(gB, dB);
    GLD16(gB + (size_t)32 * K, dB + 2048);
    GLD16(gB + (size_t)64 * K, dB + 4096);
    GLD16(gB + (size_t)96 * K, dB + 6144);
    gA += 64;
    gB += 64;
    __syncthreads();
#pragma unroll
    for (int ks = 0; ks < 2; ks++) {
      half8 af[4], bf[4];
#pragma unroll
      for (int i = 0; i < 4; i++) {
        const int rr = wm + i * 16 + fr;
        af[i] = *(const half8*)&lA[rr * 64 + (((ks * 4 + fq) ^ (rr & 7)) * 8)];
      }
#pragma unroll
      for (int j = 0; j < 4; j++) {
        const int rr = wn + j * 16 + fr;
        bf[j] = *(const half8*)&lB[rr * 64 + (((ks * 4 + fq) ^ (rr & 7)) * 8)];
      }
#pragma unroll
      for (int i = 0; i < 4; i++)
#pragma unroll
        for (int j = 0; j < 4; j++)
          acc[i][j] =
              __builtin_amdgcn_mfma_f32_16x16x32_f16(af[i], bf[j], acc[i][j], 0, 0, 0);
    }
    __syncthreads();
  }

  const int z = blockIdx.z;
#pragma unroll
  for (int i = 0; i < 4; i++)
#pragma unroll
    for (int j = 0; j < 4; j++) {
      const int col = n0 + wn + j * 16 + fr;
      const int rbase = m0 + wm + i * 16 + fq * 4;
      if (MODE == 0 && z == 0) {
        const float bv = bias[col];
#pragma unroll
        for (int r = 0; r < 4; r++)
          Cf[(size_t)(rbase + r) * 4096 + col] = acc[i][j][r] + bv;
      } else {
        _Float16* P = z ? H1 : H0;
#pragma unroll
        for (int r = 0; r < 4; r++)
          P[(size_t)(rbase + r) * 4096 + col] = (_Float16)acc[i][j][r];
      }
    }
}

// ---- prepB (fused): cvt Wre (8192 blk) + combine1 (2048 blk) ----------------
// combine1: q = (p0 + p1 + bq) * 0.125, linear [m][col] -> q-attn layout.
__global__ __launch_bounds__(256) void prepB(const float* __restrict__ Wre,
                                             _Float16* __restrict__ WreH,
                                             const _Float16* __restrict__ p0,
                                             const _Float16* __restrict__ p1,
                                             const float* __restrict__ bq,
                                             _Float16* __restrict__ q) {
  const int bid = blockIdx.x, t = threadIdx.x;
  if (bid < 8192) {
    cvt8(Wre, WreH, bid * 256 + t);
    return;
  }
  __shared__ _Float16 T[4][16][80];  // row stride 160B: 16B-aligned, bank-rotating
  const int L = t & 63, w = t >> 6;
  const int m = bid - 8192, d = w;
  const int b = m >> 9, s = m & 511;
  const size_t src = (size_t)m * 4096 + d * 1024 + L * 16;
  half8 a0 = *(const half8*)(p0 + src);
  half8 a1 = *(const half8*)(p0 + src + 8);
  half8 b0 = *(const half8*)(p1 + src);
  half8 b1 = *(const half8*)(p1 + src + 8);
  const float4* bqv = (const float4*)(bq + d * 1024 + L * 16);
  float bias[16];
#pragma unroll
  for (int c = 0; c < 4; c++) {
    float4 f = bqv[c];
    bias[c * 4 + 0] = f.x; bias[c * 4 + 1] = f.y;
    bias[c * 4 + 2] = f.z; bias[c * 4 + 3] = f.w;
  }
#pragma unroll
  for (int h = 0; h < 8; h++) {
    T[w][h][L] = (_Float16)(((float)a0[h] + (float)b0[h] + bias[h]) * 0.125f);
    T[w][h + 8][L] =
        (_Float16)(((float)a1[h] + (float)b1[h] + bias[h + 8]) * 0.125f);
  }
  const int h2 = L >> 2, c2 = L & 3;
  _Float16* dst = q + (((size_t)(b * 16 + h2) * 2048) + s * 4 + d) * 64 + c2 * 8;
  *(half8*)dst = *(const half8*)&T[w][h2][c2 * 8];
  *(half8*)(dst + 32) = *(const half8*)&T[w][h2][32 + c2 * 8];
}

// ---- combine2: out[i] += (float)p1[i], in place (element-owned, race-free) --
__global__ __launch_bounds__(256) void combine2(float* __restrict__ out,
                                                const _Float16* __restrict__ p1) {
  const int i4 = (blockIdx.x * 256 + threadIdx.x) * 4;
  float4 o = *(float4*)&out[i4];
  half4 p = *(const half4*)(p1 + i4);
  o.x += (float)p[0];
  o.y += (float)p[1];
  o.z += (float)p[2];
  o.w += (float)p[3];
  *(float4*)&out[i4] = o;
}

// ---------------- MFMA flash attention --------------------------------------
// grid (16 q-tiles, 64 bh), 256 threads = 4 waves. Q-tile 128 rows, 32/wave.
// Q[bh][2048][64] f16 (pre-scaled 1/8), Kh[bh][512][64] f16, Vt[bh][64][512] f16.
// P round-trips through wave-private LDS (C-layout -> A-layout). No barriers.
// V-tile loads for each c0 are hoisted into registers (vr[4][4]) BEFORE the
// exp/softmax VALU section so their L2 latency drains under ~400 cyc of VALU
// instead of stalling the PV MFMAs.
__global__ __launch_bounds__(256) void attn_mfma(const _Float16* __restrict__ Q,
                                                 const _Float16* __restrict__ Kh,
                                                 const _Float16* __restrict__ Vt,
                                                 float* __restrict__ Out) {
  __shared__ _Float16 Pbuf[4][32][136];
  const int t = threadIdx.x, lane = t & 63, w = t >> 6;
  const int fr = lane & 15, fq = lane >> 4;
  const int bh = blockIdx.y, qt = blockIdx.x;
  const int b = bh >> 4, h = bh & 15;

  const _Float16* Qb = Q + ((size_t)bh * 2048 + qt * 128 + w * 32) * 64;
  const _Float16* Kb = Kh + (size_t)bh * 512 * 64;
  const _Float16* Vb = Vt + (size_t)bh * 64 * 512;

  half8 qf[2][2];
#pragma unroll
  for (int i = 0; i < 2; i++)
#pragma unroll
    for (int ks = 0; ks < 2; ks++)
      qf[i][ks] = *(const half8*)(Qb + (i * 16 + fr) * 64 + ks * 32 + fq * 8);

  floatx4 oacc[2][4];
  float l_acc[2][4];
#pragma unroll
  for (int i = 0; i < 2; i++)
#pragma unroll
    for (int j = 0; j < 4; j++) {
      oacc[i][j] = (floatx4)(0.f);
      l_acc[i][j] = 0.f;
    }

  for (int c0 = 0; c0 < 512; c0 += 128) {
    floatx4 sc[2][8];
#pragma unroll
    for (int i = 0; i < 2; i++)
#pragma unroll
      for (int j = 0; j < 8; j++) sc[i][j] = (floatx4)(0.f);
#pragma unroll
    for (int j = 0; j < 8; j++) {
      const _Float16* kr = Kb + (size_t)(c0 + j * 16 + fr) * 64 + fq * 8;
      half8 k0 = *(const half8*)kr;
      half8 k1 = *(const half8*)(kr + 32);
#pragma unroll
      for (int i = 0; i < 2; i++) {
        sc[i][j] = __builtin_amdgcn_mfma_f32_16x16x32_f16(qf[i][0], k0, sc[i][j], 0, 0, 0);
        sc[i][j] = __builtin_amdgcn_mfma_f32_16x16x32_f16(qf[i][1], k1, sc[i][j], 0, 0, 0);
      }
    }
    // ---- hoisted V loads: issue all 16 before the softmax VALU section ----
    half8 vr[4][4];
#pragma unroll
    for (int kn = 0; kn < 4; kn++)
#pragma unroll
      for (int jv = 0; jv < 4; jv++)
        vr[kn][jv] =
            *(const half8*)(Vb + (size_t)(jv * 16 + fr) * 512 + c0 + kn * 32 + fq * 8);
#pragma unroll
    for (int i = 0; i < 2; i++)
#pragma unroll
      for (int j = 0; j < 8; j++)
#pragma unroll
        for (int r = 0; r < 4; r++) {
          float p = __expf(sc[i][j][r]);
          l_acc[i][r] += p;
          Pbuf[w][i * 16 + fq * 4 + r][j * 16 + fr] = (_Float16)p;
        }
#pragma unroll
    for (int kn = 0; kn < 4; kn++) {
      half8 pa[2];
#pragma unroll
      for (int i = 0; i < 2; i++)
        pa[i] = *(const half8*)&Pbuf[w][i * 16 + fr][kn * 32 + fq * 8];
#pragma unroll
      for (int jv = 0; jv < 4; jv++) {
#pragma unroll
        for (int i = 0; i < 2; i++)
          oacc[i][jv] = __builtin_amdgcn_mfma_f32_16x16x32_f16(pa[i], vr[kn][jv],
                                                              oacc[i][jv], 0, 0, 0);
      }
    }
  }

#pragma unroll
  for (int i = 0; i < 2; i++)
#pragma unroll
    for (int r = 0; r < 4; r++) {
#pragma unroll
      for (int m = 8; m; m >>= 1)
        l_acc[i][r] += __shfl_xor(l_acc[i][r], m, 16);
    }
#pragma unroll
  for (int i = 0; i < 2; i++) {
#pragma unroll
    for (int r = 0; r < 4; r++) {
      const float inv = 1.f / l_acc[i][r];
      const int m2 = qt * 128 + w * 32 + i * 16 + fq * 4 + r;
      float* orow = Out + ((size_t)(b * 512 + (m2 >> 2))) * 4096 + h * 256 + (m2 & 3) * 64 + fr;
#pragma unroll
      for (int jv = 0; jv < 4; jv++) orow[jv * 16] = oacc[i][jv][r] * inv;
    }
  }
}

// ---------------- LayerNorm over 4096, output f16 ---------------------------
__global__ __launch_bounds__(256) void ln_kernel(const float* __restrict__ X,
                                                 const float* __restrict__ g,
                                                 const float* __restrict__ bb,
                                                 _Float16* __restrict__ Y) {
  const int row = blockIdx.x;
  const int t = threadIdx.x;
  const float* x = X + (size_t)row * 4096;
  float4 vals[4];
  float sum = 0.f, sq = 0.f;
#pragma unroll
  for (int c = 0; c < 4; c++) {
    vals[c] = *(const float4*)&x[c * 1024 + t * 4];
    sum += vals[c].x + vals[c].y + vals[c].z + vals[c].w;
    sq += vals[c].x * vals[c].x + vals[c].y * vals[c].y + vals[c].z * vals[c].z +
          vals[c].w * vals[c].w;
  }
#pragma unroll
  for (int off = 32; off > 0; off >>= 1) {
    sum += __shfl_down(sum, off, 64);
    sq += __shfl_down(sq, off, 64);
  }
  __shared__ float red[8];
  const int w = t >> 6;
  if ((t & 63) == 0) {
    red[w] = sum;
    red[4 + w] = sq;
  }
  __syncthreads();
  sum = red[0] + red[1] + red[2] + red[3];
  sq = red[4] + red[5] + red[6] + red[7];
  const float mu = sum * (1.f / 4096.f);
  float var = sq * (1.f / 4096.f) - mu * mu;
  var = fmaxf(var, 0.f);
  const float rstd = rsqrtf(var + 1e-12f);
#pragma unroll
  for (int c = 0; c < 4; c++) {
    const int j = c * 1024 + t * 4;
    float4 gg = *(const float4*)&g[j];
    float4 bv = *(const float4*)&bb[j];
    half4 y;
    y[0] = (_Float16)((vals[c].x - mu) * rstd * gg.x + bv.x);
    y[1] = (_Float16)((vals[c].y - mu) * rstd * gg.y + bv.y);
    y[2] = (_Float16)((vals[c].z - mu) * rstd * gg.z + bv.z);
    y[3] = (_Float16)((vals[c].w - mu) * rstd * gg.w + bv.w);
    *(half4*)&Y[(size_t)row * 4096 + j] = y;
  }
}

// ---------------- launcher --------------------------------------------------
extern "C" void kernel_launch(void* const* d_in, const int* in_sizes, int n_in,
                              void* d_out, int out_size, void* d_ws,
                              size_t ws_size, hipStream_t stream) {
  const float* emb = (const float*)d_in[0];
  const float* keys = (const float*)d_in[1];
  const float* values = (const float*)d_in[2];
  const float* Wq = (const float*)d_in[3];
  const float* bq = (const float*)d_in[4];
  const float* Wre = (const float*)d_in[5];
  const float* bre = (const float*)d_in[6];
  const float* ln_g = (const float*)d_in[7];
  const float* ln_b = (const float*)d_in[8];
  float* out = (float*)d_out;

  char* ws = (char*)d_ws;
  _Float16* embH = (_Float16*)(ws);
  _Float16* WqH = (_Float16*)(ws + ((size_t)16 << 20));
  _Float16* Kh = (_Float16*)(ws + ((size_t)48 << 20));
  _Float16* Vt = (_Float16*)(ws + ((size_t)52 << 20));
  _Float16* P0q = (_Float16*)d_out;
  _Float16* P1q = (_Float16*)((char*)d_out + ((size_t)16 << 20));
  _Float16* WreH = WqH;
  _Float16* qattn = (_Float16*)(ws);
  _Float16* lnH = (_Float16*)(ws + ((size_t)48 << 20));
  _Float16* P1o = (_Float16*)(ws);

  prepA<<<20480, 256, 0, stream>>>(emb, Wq, keys, values, embH, WqH, Kh, Vt);
  gemm_bt<1><<<dim3(32, 16, 2), 256, 0, stream>>>(embH, WqH, nullptr, nullptr,
                                                  P0q, P1q);
  prepB<<<10240, 256, 0, stream>>>(Wre, WreH, P0q, P1q, bq, qattn);
  attn_mfma<<<dim3(16, 64), 256, 0, stream>>>(qattn, Kh, Vt, out);
  ln_kernel<<<2048, 256, 0, stream>>>(out, ln_g, ln_b, lnH);
  gemm_bt<0><<<dim3(32, 16, 2), 256, 0, stream>>>(lnH, WreH, bre, out, nullptr,
                                                  P1o);
  combine2<<<8192, 256, 0, stream>>>(out, P1o);
}

// Round 3
// 453.341 us; speedup vs baseline: 1.0247x; 1.0247x over previous
//
#include <hip/hip_runtime.h>

typedef __attribute__((ext_vector_type(8))) _Float16 half8;
typedef __attribute__((ext_vector_type(4))) _Float16 half4;
typedef __attribute__((ext_vector_type(4))) float    floatx4;

#define GLD16(g, l)                                                            \
  __builtin_amdgcn_global_load_lds(                                            \
      (const __attribute__((address_space(1))) void*)(g),                      \
      (__attribute__((address_space(3))) void*)(l), 16, 0, 0)

#define MFMA16(a, b, c) __builtin_amdgcn_mfma_f32_16x16x32_f16(a, b, c, 0, 0, 0)

__device__ __forceinline__ void cvt8(const float* __restrict__ in,
                                     _Float16* __restrict__ out, int i) {
  const float4* p = (const float4*)in + (size_t)i * 2;
  float4 a = p[0], b = p[1];
  half8 h;
  h[0] = (_Float16)a.x; h[1] = (_Float16)a.y; h[2] = (_Float16)a.z; h[3] = (_Float16)a.w;
  h[4] = (_Float16)b.x; h[5] = (_Float16)b.y; h[6] = (_Float16)b.z; h[7] = (_Float16)b.w;
  *(half8*)(out + (size_t)i * 8) = h;
}

// ---- prepA (fused): cvt emb (4096 blk) + cvt Wq (8192 blk) + prep_kv (8192) -
__global__ __launch_bounds__(256) void prepA(const float* __restrict__ emb,
                                             const float* __restrict__ Wq,
                                             const float* __restrict__ keys,
                                             const float* __restrict__ values,
                                             _Float16* __restrict__ embH,
                                             _Float16* __restrict__ WqH,
                                             _Float16* __restrict__ Kh,
                                             _Float16* __restrict__ Vt) {
  const int bid = blockIdx.x, t = threadIdx.x;
  if (bid < 4096) {
    cvt8(emb, embH, bid * 256 + t);
  } else if (bid < 12288) {
    cvt8(Wq, WqH, (bid - 4096) * 256 + t);
  } else {
    const int tid = (bid - 12288) * 256 + t;  // < 2M
    {
      int v = tid & 63, n = (tid >> 6) & 511, h = (tid >> 15) & 15, b = tid >> 19;
      Kh[tid] = (_Float16)keys[((size_t)(b * 512 + n)) * 1024 + v * 16 + h];
    }
    {
      int n = tid & 511, v = (tid >> 9) & 63, h = (tid >> 15) & 15, b = tid >> 19;
      Vt[tid] = (_Float16)values[((size_t)(b * 512 + n)) * 1024 + v * 16 + h];
    }
  }
}

// ---------------- GEMM_BT split-K, 256x256 tile, 8-wave, 4-phase ------------
// C[m,n] = sum_k A[m,k]*B[n,k]. M=2048, N=4096, K=4096 split in 2 (blockIdx.z),
// NT=32 K-tiles of BK=64. 512 threads = 8 waves (2M x 4N), per-wave 128x64.
// LDS 128 KiB: lA[2][256][64] + lB[2][256][64] f16, XOR chunk swizzle (chunk c
// of row r at slot c^(r&7)) applied on the global SOURCE address.
// Phase schedule (reads 12/8/4/0, MFMA 16/16/16/16 per phase):
//   P0: stage (t+1).B.h1 [other buf] | read af0-3 (8) + bf01 (4) | QUAD(i0-3,j0-1)
//   P1:                              | read af4-7 (8)            | QUAD(i4-7,j0-1)
//   P2: stage (t+2).A.h0 [cur buf]   | read bf23 (4)             | QUAD(i0-3,j2-3)
//   P3: stage (t+2).A.h1 + (t+2).B.h0 [cur buf]                  | QUAD(i4-7,j2-3)
//       then s_waitcnt vmcnt(6)
// Region death (last ds_read): A after P1 -> (t+2).A stages at P2/P3 legal;
// B after P2 -> (t+2).B.h0 at P3 legal; other-buf B.h1 dead since (t-1).P2.
// vmcnt(6) at end of tile t retires everything except the 3 newest half-tiles
// (t.P2 + t.P3 x2) => tile t+1 fully resident at its start; never vmcnt(0) in
// the loop. Tail staging is k-clamped (rewrites dead regions, keeps counts
// uniform so the vmcnt arithmetic stays exact).
// MODE 1 (gemm1): z=0 -> H0 f16 linear, z=1 -> H1 f16 linear (no bias)
// MODE 0 (gemm2): z=0 -> Cf f32 linear + bias[col], z=1 -> H1 f16 linear
template <int MODE>
__global__ __launch_bounds__(512, 2) void gemm_bt(const _Float16* __restrict__ A,
                                                  const _Float16* __restrict__ Bw,
                                                  const float* __restrict__ bias,
                                                  float* __restrict__ Cf,
                                                  _Float16* __restrict__ H0,
                                                  _Float16* __restrict__ H1) {
  const int K = 4096;
  const int NT = 32;
  __shared__ _Float16 lA[2 * 16384];
  __shared__ _Float16 lB[2 * 16384];
  const int t = threadIdx.x, lane = t & 63, w = t >> 6;
  const int m0 = blockIdx.y * 256, n0 = blockIdx.x * 256;
  const int kb = blockIdx.z * 2048;
  const int wm = (w >> 2) * 128, wn = (w & 3) * 64;
  const int fr = lane & 15, fq = lane >> 4;

  const int srow = t >> 3;                 // 0..63 (64 rows per GLD)
  const int sch = (t & 7) ^ (srow & 7);    // swizzled source chunk
  const _Float16* gA = A + (size_t)(m0 + srow) * K + kb + sch * 8;
  const _Float16* gB = Bw + (size_t)(n0 + srow) * K + kb + sch * 8;
  _Float16* dA = &lA[t * 8];
  _Float16* dB = &lB[t * 8];

// stage one half-tile (=2 GLD): op 0=A 1=B, buffer bf_, k-tile kt_, half h_
#define STG(op, bf_, kt_, h_)                                                  \
  do {                                                                         \
    const _Float16* g_ = (op ? gB : gA) + (size_t)((h_)*128) * K + (kt_)*64;   \
    _Float16* d_ = (op ? dB : dA) + (bf_)*16384 + (h_)*8192;                   \
    GLD16(g_, d_);                                                             \
    GLD16(g_ + (size_t)64 * K, d_ + 4096);                                     \
  } while (0)

  // prologue: tile0 (4 ht) + tile1 A.h0/A.h1/B.h0 (3 ht) = 14 GLD;
  // vmcnt(6) retires the 8 oldest = all of tile0. Tile1's 3 ht stay in flight
  // (steady-state invariant); (1).B.h1 is staged at t=0's P0.
  STG(0, 0, 0, 0); STG(0, 0, 0, 1); STG(1, 0, 0, 0); STG(1, 0, 0, 1);
  STG(0, 1, 1, 0); STG(0, 1, 1, 1); STG(1, 1, 1, 0);
  asm volatile("s_waitcnt vmcnt(6)" ::: "memory");
  __builtin_amdgcn_s_barrier();

  floatx4 acc[8][4];
#pragma unroll
  for (int i = 0; i < 8; i++)
#pragma unroll
    for (int j = 0; j < 4; j++) acc[i][j] = (floatx4)(0.f);

  // per-wave LDS read bases; XOR term is row-invariant (wm,wn,i*16 ≡ 0 mod 8)
  const _Float16* cA = lA + (wm + fr) * 64;
  const _Float16* cB = lB + (wn + fr) * 64;
  const int xo0 = ((fq) ^ (fr & 7)) * 8;
  const int xo1 = ((4 + fq) ^ (fr & 7)) * 8;

#define QUAD(ibase, jbase)                                                     \
  do {                                                                         \
    __builtin_amdgcn_s_setprio(1);                                             \
    _Pragma("unroll") for (int i_ = 0; i_ < 4; i_++) {                         \
      _Pragma("unroll") for (int jj_ = 0; jj_ < 2; jj_++) {                    \
        acc[(ibase) + i_][(jbase) + jj_] =                                     \
            MFMA16(af[(ibase) + i_][0], bf[jj_][0], acc[(ibase) + i_][(jbase) + jj_]); \
        acc[(ibase) + i_][(jbase) + jj_] =                                     \
            MFMA16(af[(ibase) + i_][1], bf[jj_][1], acc[(ibase) + i_][(jbase) + jj_]); \
      }                                                                        \
    }                                                                          \
    __builtin_amdgcn_s_setprio(0);                                             \
  } while (0)

  for (int tt = 0; tt < NT; ++tt) {
    const int buf = tt & 1;
    const int o = buf * 16384;
    const int kt1 = tt + 1 < NT ? tt + 1 : NT - 1;
    const int kt2 = tt + 2 < NT ? tt + 2 : NT - 1;
    half8 af[8][2], bf[2][2];

    // ---- P0: stage (t+1).B.h1; read af0-3 + bf01; MFMA (i0-3 x j0-1)
    STG(1, buf ^ 1, kt1, 1);
#pragma unroll
    for (int i = 0; i < 4; i++) {
      af[i][0] = *(const half8*)(cA + o + i * 1024 + xo0);
      af[i][1] = *(const half8*)(cA + o + i * 1024 + xo1);
    }
#pragma unroll
    for (int jj = 0; jj < 2; jj++) {
      bf[jj][0] = *(const half8*)(cB + o + jj * 1024 + xo0);
      bf[jj][1] = *(const half8*)(cB + o + jj * 1024 + xo1);
    }
    __builtin_amdgcn_s_barrier();
    asm volatile("s_waitcnt lgkmcnt(0)" ::: "memory");
    __builtin_amdgcn_sched_barrier(0);
    QUAD(0, 0);
    __builtin_amdgcn_s_barrier();

    // ---- P1: read af4-7; MFMA (i4-7 x j0-1)
#pragma unroll
    for (int i = 4; i < 8; i++) {
      af[i][0] = *(const half8*)(cA + o + i * 1024 + xo0);
      af[i][1] = *(const half8*)(cA + o + i * 1024 + xo1);
    }
    __builtin_amdgcn_s_barrier();
    asm volatile("s_waitcnt lgkmcnt(0)" ::: "memory");
    __builtin_amdgcn_sched_barrier(0);
    QUAD(4, 0);
    __builtin_amdgcn_s_barrier();

    // ---- P2: stage (t+2).A.h0 (A dead after P1); read bf23; MFMA (i0-3 x j2-3)
    STG(0, buf, kt2, 0);
    bf[0][0] = *(const half8*)(cB + o + 2 * 1024 + xo0);
    bf[0][1] = *(const half8*)(cB + o + 2 * 1024 + xo1);
    bf[1][0] = *(const half8*)(cB + o + 3 * 1024 + xo0);
    bf[1][1] = *(const half8*)(cB + o + 3 * 1024 + xo1);
    __builtin_amdgcn_s_barrier();
    asm volatile("s_waitcnt lgkmcnt(0)" ::: "memory");
    __builtin_amdgcn_sched_barrier(0);
    QUAD(0, 2);
    __builtin_amdgcn_s_barrier();

    // ---- P3: stage (t+2).A.h1 + (t+2).B.h0 (B dead after P2); MFMA (i4-7 x j2-3)
    STG(0, buf, kt2, 1);
    STG(1, buf, kt2, 0);
    __builtin_amdgcn_s_barrier();
    __builtin_amdgcn_sched_barrier(0);
    QUAD(4, 2);
    asm volatile("s_waitcnt vmcnt(6)" ::: "memory");
    __builtin_amdgcn_s_barrier();
  }

  const int z = blockIdx.z;
#pragma unroll
  for (int i = 0; i < 8; i++)
#pragma unroll
    for (int j = 0; j < 4; j++) {
      const int col = n0 + wn + j * 16 + fr;
      const int rbase = m0 + wm + i * 16 + fq * 4;
      if (MODE == 0 && z == 0) {
        const float bv = bias[col];
#pragma unroll
        for (int r = 0; r < 4; r++)
          Cf[(size_t)(rbase + r) * 4096 + col] = acc[i][j][r] + bv;
      } else {
        _Float16* P = z ? H1 : H0;
#pragma unroll
        for (int r = 0; r < 4; r++)
          P[(size_t)(rbase + r) * 4096 + col] = (_Float16)acc[i][j][r];
      }
    }
#undef QUAD
#undef STG
}

// ---- prepB (fused): cvt Wre (8192 blk) + combine1 (2048 blk) ----------------
// combine1: q = (p0 + p1 + bq) * 0.125, linear [m][col] -> q-attn layout.
__global__ __launch_bounds__(256) void prepB(const float* __restrict__ Wre,
                                             _Float16* __restrict__ WreH,
                                             const _Float16* __restrict__ p0,
                                             const _Float16* __restrict__ p1,
                                             const float* __restrict__ bq,
                                             _Float16* __restrict__ q) {
  const int bid = blockIdx.x, t = threadIdx.x;
  if (bid < 8192) {
    cvt8(Wre, WreH, bid * 256 + t);
    return;
  }
  __shared__ _Float16 T[4][16][80];  // row stride 160B: 16B-aligned, bank-rotating
  const int L = t & 63, w = t >> 6;
  const int m = bid - 8192, d = w;
  const int b = m >> 9, s = m & 511;
  const size_t src = (size_t)m * 4096 + d * 1024 + L * 16;
  half8 a0 = *(const half8*)(p0 + src);
  half8 a1 = *(const half8*)(p0 + src + 8);
  half8 b0 = *(const half8*)(p1 + src);
  half8 b1 = *(const half8*)(p1 + src + 8);
  const float4* bqv = (const float4*)(bq + d * 1024 + L * 16);
  float bias[16];
#pragma unroll
  for (int c = 0; c < 4; c++) {
    float4 f = bqv[c];
    bias[c * 4 + 0] = f.x; bias[c * 4 + 1] = f.y;
    bias[c * 4 + 2] = f.z; bias[c * 4 + 3] = f.w;
  }
#pragma unroll
  for (int h = 0; h < 8; h++) {
    T[w][h][L] = (_Float16)(((float)a0[h] + (float)b0[h] + bias[h]) * 0.125f);
    T[w][h + 8][L] =
        (_Float16)(((float)a1[h] + (float)b1[h] + bias[h + 8]) * 0.125f);
  }
  const int h2 = L >> 2, c2 = L & 3;
  _Float16* dst = q + (((size_t)(b * 16 + h2) * 2048) + s * 4 + d) * 64 + c2 * 8;
  *(half8*)dst = *(const half8*)&T[w][h2][c2 * 8];
  *(half8*)(dst + 32) = *(const half8*)&T[w][h2][32 + c2 * 8];
}

// ---- combine2: out[i] += (float)p1[i], in place (element-owned, race-free) --
__global__ __launch_bounds__(256) void combine2(float* __restrict__ out,
                                                const _Float16* __restrict__ p1) {
  const int i4 = (blockIdx.x * 256 + threadIdx.x) * 4;
  float4 o = *(float4*)&out[i4];
  half4 p = *(const half4*)(p1 + i4);
  o.x += (float)p[0];
  o.y += (float)p[1];
  o.z += (float)p[2];
  o.w += (float)p[3];
  *(float4*)&out[i4] = o;
}

// ---------------- MFMA flash attention --------------------------------------
// grid (16 q-tiles, 64 bh), 256 threads = 4 waves. Q-tile 128 rows, 32/wave.
// V-tile loads hoisted into registers before the exp/softmax VALU section so
// their L2 latency drains under ~400 cyc of VALU instead of stalling PV MFMAs.
__global__ __launch_bounds__(256) void attn_mfma(const _Float16* __restrict__ Q,
                                                 const _Float16* __restrict__ Kh,
                                                 const _Float16* __restrict__ Vt,
                                                 float* __restrict__ Out) {
  __shared__ _Float16 Pbuf[4][32][136];
  const int t = threadIdx.x, lane = t & 63, w = t >> 6;
  const int fr = lane & 15, fq = lane >> 4;
  const int bh = blockIdx.y, qt = blockIdx.x;
  const int b = bh >> 4, h = bh & 15;

  const _Float16* Qb = Q + ((size_t)bh * 2048 + qt * 128 + w * 32) * 64;
  const _Float16* Kb = Kh + (size_t)bh * 512 * 64;
  const _Float16* Vb = Vt + (size_t)bh * 64 * 512;

  half8 qf[2][2];
#pragma unroll
  for (int i = 0; i < 2; i++)
#pragma unroll
    for (int ks = 0; ks < 2; ks++)
      qf[i][ks] = *(const half8*)(Qb + (i * 16 + fr) * 64 + ks * 32 + fq * 8);

  floatx4 oacc[2][4];
  float l_acc[2][4];
#pragma unroll
  for (int i = 0; i < 2; i++)
#pragma unroll
    for (int j = 0; j < 4; j++) {
      oacc[i][j] = (floatx4)(0.f);
      l_acc[i][j] = 0.f;
    }

  for (int c0 = 0; c0 < 512; c0 += 128) {
    floatx4 sc[2][8];
#pragma unroll
    for (int i = 0; i < 2; i++)
#pragma unroll
      for (int j = 0; j < 8; j++) sc[i][j] = (floatx4)(0.f);
#pragma unroll
    for (int j = 0; j < 8; j++) {
      const _Float16* kr = Kb + (size_t)(c0 + j * 16 + fr) * 64 + fq * 8;
      half8 k0 = *(const half8*)kr;
      half8 k1 = *(const half8*)(kr + 32);
#pragma unroll
      for (int i = 0; i < 2; i++) {
        sc[i][j] = __builtin_amdgcn_mfma_f32_16x16x32_f16(qf[i][0], k0, sc[i][j], 0, 0, 0);
        sc[i][j] = __builtin_amdgcn_mfma_f32_16x16x32_f16(qf[i][1], k1, sc[i][j], 0, 0, 0);
      }
    }
    // ---- hoisted V loads: issue all 16 before the softmax VALU section ----
    half8 vr[4][4];
#pragma unroll
    for (int kn = 0; kn < 4; kn++)
#pragma unroll
      for (int jv = 0; jv < 4; jv++)
        vr[kn][jv] =
            *(const half8*)(Vb + (size_t)(jv * 16 + fr) * 512 + c0 + kn * 32 + fq * 8);
#pragma unroll
    for (int i = 0; i < 2; i++)
#pragma unroll
      for (int j = 0; j < 8; j++)
#pragma unroll
        for (int r = 0; r < 4; r++) {
          float p = __expf(sc[i][j][r]);
          l_acc[i][r] += p;
          Pbuf[w][i * 16 + fq * 4 + r][j * 16 + fr] = (_Float16)p;
        }
#pragma unroll
    for (int kn = 0; kn < 4; kn++) {
      half8 pa[2];
#pragma unroll
      for (int i = 0; i < 2; i++)
        pa[i] = *(const half8*)&Pbuf[w][i * 16 + fr][kn * 32 + fq * 8];
#pragma unroll
      for (int jv = 0; jv < 4; jv++) {
#pragma unroll
        for (int i = 0; i < 2; i++)
          oacc[i][jv] = __builtin_amdgcn_mfma_f32_16x16x32_f16(pa[i], vr[kn][jv],
                                                              oacc[i][jv], 0, 0, 0);
      }
    }
  }

#pragma unroll
  for (int i = 0; i < 2; i++)
#pragma unroll
    for (int r = 0; r < 4; r++) {
#pragma unroll
      for (int m = 8; m; m >>= 1)
        l_acc[i][r] += __shfl_xor(l_acc[i][r], m, 16);
    }
#pragma unroll
  for (int i = 0; i < 2; i++) {
#pragma unroll
    for (int r = 0; r < 4; r++) {
      const float inv = 1.f / l_acc[i][r];
      const int m2 = qt * 128 + w * 32 + i * 16 + fq * 4 + r;
      float* orow = Out + ((size_t)(b * 512 + (m2 >> 2))) * 4096 + h * 256 + (m2 & 3) * 64 + fr;
#pragma unroll
      for (int jv = 0; jv < 4; jv++) orow[jv * 16] = oacc[i][jv][r] * inv;
    }
  }
}

// ---------------- LayerNorm over 4096, output f16 ---------------------------
__global__ __launch_bounds__(256) void ln_kernel(const float* __restrict__ X,
                                                 const float* __restrict__ g,
                                                 const float* __restrict__ bb,
                                                 _Float16* __restrict__ Y) {
  const int row = blockIdx.x;
  const int t = threadIdx.x;
  const float* x = X + (size_t)row * 4096;
  float4 vals[4];
  float sum = 0.f, sq = 0.f;
#pragma unroll
  for (int c = 0; c < 4; c++) {
    vals[c] = *(const float4*)&x[c * 1024 + t * 4];
    sum += vals[c].x + vals[c].y + vals[c].z + vals[c].w;
    sq += vals[c].x * vals[c].x + vals[c].y * vals[c].y + vals[c].z * vals[c].z +
          vals[c].w * vals[c].w;
  }
#pragma unroll
  for (int off = 32; off > 0; off >>= 1) {
    sum += __shfl_down(sum, off, 64);
    sq += __shfl_down(sq, off, 64);
  }
  __shared__ float red[8];
  const int w = t >> 6;
  if ((t & 63) == 0) {
    red[w] = sum;
    red[4 + w] = sq;
  }
  __syncthreads();
  sum = red[0] + red[1] + red[2] + red[3];
  sq = red[4] + red[5] + red[6] + red[7];
  const float mu = sum * (1.f / 4096.f);
  float var = sq * (1.f / 4096.f) - mu * mu;
  var = fmaxf(var, 0.f);
  const float rstd = rsqrtf(var + 1e-12f);
#pragma unroll
  for (int c = 0; c < 4; c++) {
    const int j = c * 1024 + t * 4;
    float4 gg = *(const float4*)&g[j];
    float4 bv = *(const float4*)&bb[j];
    half4 y;
    y[0] = (_Float16)((vals[c].x - mu) * rstd * gg.x + bv.x);
    y[1] = (_Float16)((vals[c].y - mu) * rstd * gg.y + bv.y);
    y[2] = (_Float16)((vals[c].z - mu) * rstd * gg.z + bv.z);
    y[3] = (_Float16)((vals[c].w - mu) * rstd * gg.w + bv.w);
    *(half4*)&Y[(size_t)row * 4096 + j] = y;
  }
}

// ---------------- launcher --------------------------------------------------
extern "C" void kernel_launch(void* const* d_in, const int* in_sizes, int n_in,
                              void* d_out, int out_size, void* d_ws,
                              size_t ws_size, hipStream_t stream) {
  const float* emb = (const float*)d_in[0];
  const float* keys = (const float*)d_in[1];
  const float* values = (const float*)d_in[2];
  const float* Wq = (const float*)d_in[3];
  const float* bq = (const float*)d_in[4];
  const float* Wre = (const float*)d_in[5];
  const float* bre = (const float*)d_in[6];
  const float* ln_g = (const float*)d_in[7];
  const float* ln_b = (const float*)d_in[8];
  float* out = (float*)d_out;

  char* ws = (char*)d_ws;
  _Float16* embH = (_Float16*)(ws);
  _Float16* WqH = (_Float16*)(ws + ((size_t)16 << 20));
  _Float16* Kh = (_Float16*)(ws + ((size_t)48 << 20));
  _Float16* Vt = (_Float16*)(ws + ((size_t)52 << 20));
  _Float16* P0q = (_Float16*)d_out;
  _Float16* P1q = (_Float16*)((char*)d_out + ((size_t)16 << 20));
  _Float16* WreH = WqH;
  _Float16* qattn = (_Float16*)(ws);
  _Float16* lnH = (_Float16*)(ws + ((size_t)48 << 20));
  _Float16* P1o = (_Float16*)(ws);

  prepA<<<20480, 256, 0, stream>>>(emb, Wq, keys, values, embH, WqH, Kh, Vt);
  gemm_bt<1><<<dim3(16, 8, 2), 512, 0, stream>>>(embH, WqH, nullptr, nullptr,
                                                 P0q, P1q);
  prepB<<<10240, 256, 0, stream>>>(Wre, WreH, P0q, P1q, bq, qattn);
  attn_mfma<<<dim3(16, 64), 256, 0, stream>>>(qattn, Kh, Vt, out);
  ln_kernel<<<2048, 256, 0, stream>>>(out, ln_g, ln_b, lnH);
  gemm_bt<0><<<dim3(16, 8, 2), 512, 0, stream>>>(lnH, WreH, bre, out, nullptr,
                                                 P1o);
  combine2<<<8192, 256, 0, stream>>>(out, P1o);
}

// Round 4
// 443.836 us; speedup vs baseline: 1.0466x; 1.0214x over previous
//
#include <hip/hip_runtime.h>

typedef __attribute__((ext_vector_type(8))) _Float16 half8;
typedef __attribute__((ext_vector_type(4))) _Float16 half4;
typedef __attribute__((ext_vector_type(4))) float    floatx4;

#define GLD16(g, l)                                                            \
  __builtin_amdgcn_global_load_lds(                                            \
      (const __attribute__((address_space(1))) void*)(g),                      \
      (__attribute__((address_space(3))) void*)(l), 16, 0, 0)

#define MFMA16(a, b, c) __builtin_amdgcn_mfma_f32_16x16x32_f16(a, b, c, 0, 0, 0)

__device__ __forceinline__ void cvt8(const float* __restrict__ in,
                                     _Float16* __restrict__ out, int i) {
  const float4* p = (const float4*)in + (size_t)i * 2;
  float4 a = p[0], b = p[1];
  half8 h;
  h[0] = (_Float16)a.x; h[1] = (_Float16)a.y; h[2] = (_Float16)a.z; h[3] = (_Float16)a.w;
  h[4] = (_Float16)b.x; h[5] = (_Float16)b.y; h[6] = (_Float16)b.z; h[7] = (_Float16)b.w;
  *(half8*)(out + (size_t)i * 8) = h;
}

// ---- prepA (fused): cvt emb (4096 blk) + cvt Wq (8192 blk) + prep_kv (8192) -
__global__ __launch_bounds__(256) void prepA(const float* __restrict__ emb,
                                             const float* __restrict__ Wq,
                                             const float* __restrict__ keys,
                                             const float* __restrict__ values,
                                             _Float16* __restrict__ embH,
                                             _Float16* __restrict__ WqH,
                                             _Float16* __restrict__ Kh,
                                             _Float16* __restrict__ Vt) {
  const int bid = blockIdx.x, t = threadIdx.x;
  if (bid < 4096) {
    cvt8(emb, embH, bid * 256 + t);
  } else if (bid < 12288) {
    cvt8(Wq, WqH, (bid - 4096) * 256 + t);
  } else {
    const int tid = (bid - 12288) * 256 + t;  // < 2M
    {
      int v = tid & 63, n = (tid >> 6) & 511, h = (tid >> 15) & 15, b = tid >> 19;
      Kh[tid] = (_Float16)keys[((size_t)(b * 512 + n)) * 1024 + v * 16 + h];
    }
    {
      int n = tid & 511, v = (tid >> 9) & 63, h = (tid >> 15) & 15, b = tid >> 19;
      Vt[tid] = (_Float16)values[((size_t)(b * 512 + n)) * 1024 + v * 16 + h];
    }
  }
}

// ---------------- GEMM_BT split-K, 256x256 tile, 8-wave, 4-phase ------------
// C[m,n] = sum_k A[m,k]*B[n,k]. M=2048, N=4096, K=4096 split in 2 (blockIdx.z),
// NT=32 K-tiles of BK=64. 512 threads = 8 waves (2M x 4N), per-wave 128x64.
// LDS 128 KiB: lA[2][256][64] + lB[2][256][64] f16, XOR chunk swizzle (chunk c
// of row r at slot c^(r&7)) applied on the global SOURCE address.
// Phase schedule (reads 12/8/4/0, MFMA 16/16/16/16), ONE barrier per phase:
//   P0: stage (t+1).B.h1 [other buf] | read af0-3+bf01 | QUAD(i0-3,j0-1) | BAR
//   P1:                              | read af4-7      | QUAD(i4-7,j0-1) | BAR
//   P2: stage (t+2).A.h0 [cur buf]   | read bf23       | QUAD(i0-3,j2-3) | BAR
//   P3: stage (t+2).A.h1 + (t+2).B.h0 [cur buf]        | QUAD(i4-7,j2-3)
//       | s_waitcnt vmcnt(6) | BAR
// NO asm lgkmcnt / sched_barrier: reads are compiler-visible half8 loads, so
// the compiler emits fine-grained counted lgkmcnt before each consuming MFMA
// (m97 behavior) instead of a drain-all stall. Phase-top barriers removed:
// hazard proof — every STG targets a region whose last reader finished its
// QUAD (hence its reads) before the end-of-phase barrier that precedes the
// STG issue: (t+2).A.h0/h1 readers (af, P0/P1) < BAR(P1) < STG@P2/P3;
// (t+2).B.h0 readers (bf23, P2) < BAR(P2) < STG@P3; (t+1).B.h1 [buf^1] last
// read at P2 of tile t-1 < BAR(P3,t-1) < STG@P0(t). vmcnt(6) once per tile:
// each wave drains its own 8 GLD/tile slice; the following barrier makes the
// residency guarantee collective. Tail stages are k-clamped (byte-identical
// rewrites, keeps vmcnt counts uniform).
// MODE 1 (gemm1): z=0 -> H0 f16 linear, z=1 -> H1 f16 linear (no bias)
// MODE 0 (gemm2): z=0 -> Cf f32 linear + bias[col], z=1 -> H1 f16 linear
template <int MODE>
__global__ __launch_bounds__(512, 2) void gemm_bt(const _Float16* __restrict__ A,
                                                  const _Float16* __restrict__ Bw,
                                                  const float* __restrict__ bias,
                                                  float* __restrict__ Cf,
                                                  _Float16* __restrict__ H0,
                                                  _Float16* __restrict__ H1) {
  const int K = 4096;
  const int NT = 32;
  __shared__ _Float16 lA[2 * 16384];
  __shared__ _Float16 lB[2 * 16384];
  const int t = threadIdx.x, lane = t & 63, w = t >> 6;
  const int m0 = blockIdx.y * 256, n0 = blockIdx.x * 256;
  const int kb = blockIdx.z * 2048;
  const int wm = (w >> 2) * 128, wn = (w & 3) * 64;
  const int fr = lane & 15, fq = lane >> 4;

  const int srow = t >> 3;                 // 0..63 (64 rows per GLD)
  const int sch = (t & 7) ^ (srow & 7);    // swizzled source chunk
  const _Float16* gA = A + (size_t)(m0 + srow) * K + kb + sch * 8;
  const _Float16* gB = Bw + (size_t)(n0 + srow) * K + kb + sch * 8;
  _Float16* dA = &lA[t * 8];
  _Float16* dB = &lB[t * 8];

// stage one half-tile (=2 GLD): op 0=A 1=B, buffer bf_, k-tile kt_, half h_
#define STG(op, bf_, kt_, h_)                                                  \
  do {                                                                         \
    const _Float16* g_ = (op ? gB : gA) + (size_t)((h_)*128) * K + (kt_)*64;   \
    _Float16* d_ = (op ? dB : dA) + (bf_)*16384 + (h_)*8192;                   \
    GLD16(g_, d_);                                                             \
    GLD16(g_ + (size_t)64 * K, d_ + 4096);                                     \
  } while (0)

  // prologue: tile0 (4 ht) + tile1 A.h0/A.h1/B.h0 (3 ht) = 14 GLD;
  // vmcnt(6) retires the 8 oldest = all of tile0. Tile1's 3 ht stay in flight
  // (steady-state invariant); (1).B.h1 is staged at t=0's P0.
  STG(0, 0, 0, 0); STG(0, 0, 0, 1); STG(1, 0, 0, 0); STG(1, 0, 0, 1);
  STG(0, 1, 1, 0); STG(0, 1, 1, 1); STG(1, 1, 1, 0);
  asm volatile("s_waitcnt vmcnt(6)" ::: "memory");
  __builtin_amdgcn_s_barrier();

  floatx4 acc[8][4];
#pragma unroll
  for (int i = 0; i < 8; i++)
#pragma unroll
    for (int j = 0; j < 4; j++) acc[i][j] = (floatx4)(0.f);

  // per-wave LDS read bases; XOR term is row-invariant (wm,wn,i*16 ≡ 0 mod 8)
  const _Float16* cA = lA + (wm + fr) * 64;
  const _Float16* cB = lB + (wn + fr) * 64;
  const int xo0 = ((fq) ^ (fr & 7)) * 8;
  const int xo1 = ((4 + fq) ^ (fr & 7)) * 8;

#define QUAD(ibase, jbase)                                                     \
  do {                                                                         \
    __builtin_amdgcn_s_setprio(1);                                             \
    _Pragma("unroll") for (int i_ = 0; i_ < 4; i_++) {                         \
      _Pragma("unroll") for (int jj_ = 0; jj_ < 2; jj_++) {                    \
        acc[(ibase) + i_][(jbase) + jj_] =                                     \
            MFMA16(af[(ibase) + i_][0], bf[jj_][0], acc[(ibase) + i_][(jbase) + jj_]); \
        acc[(ibase) + i_][(jbase) + jj_] =                                     \
            MFMA16(af[(ibase) + i_][1], bf[jj_][1], acc[(ibase) + i_][(jbase) + jj_]); \
      }                                                                        \
    }                                                                          \
    __builtin_amdgcn_s_setprio(0);                                             \
  } while (0)

#define TILE(BUF, TT)                                                          \
  do {                                                                         \
    const int kt1 = ((TT) + 1 < NT) ? (TT) + 1 : NT - 1;                       \
    const int kt2 = ((TT) + 2 < NT) ? (TT) + 2 : NT - 1;                       \
    const int o = (BUF)*16384;                                                 \
    half8 af[8][2], bf[2][2];                                                  \
    /* P0: stage (t+1).B.h1; read af0-3+bf01; MFMA */                          \
    STG(1, (BUF) ^ 1, kt1, 1);                                                 \
    _Pragma("unroll") for (int i = 0; i < 4; i++) {                            \
      af[i][0] = *(const half8*)(cA + o + i * 1024 + xo0);                     \
      af[i][1] = *(const half8*)(cA + o + i * 1024 + xo1);                     \
    }                                                                          \
    _Pragma("unroll") for (int jj = 0; jj < 2; jj++) {                         \
      bf[jj][0] = *(const half8*)(cB + o + jj * 1024 + xo0);                   \
      bf[jj][1] = *(const half8*)(cB + o + jj * 1024 + xo1);                   \
    }                                                                          \
    QUAD(0, 0);                                                                \
    __builtin_amdgcn_s_barrier();                                              \
    /* P1: read af4-7; MFMA */                                                 \
    _Pragma("unroll") for (int i = 4; i < 8; i++) {                            \
      af[i][0] = *(const half8*)(cA + o + i * 1024 + xo0);                     \
      af[i][1] = *(const half8*)(cA + o + i * 1024 + xo1);                     \
    }                                                                          \
    QUAD(4, 0);                                                                \
    __builtin_amdgcn_s_barrier();                                              \
    /* P2: stage (t+2).A.h0; read bf23; MFMA */                                \
    STG(0, (BUF), kt2, 0);                                                     \
    bf[0][0] = *(const half8*)(cB + o + 2 * 1024 + xo0);                       \
    bf[0][1] = *(const half8*)(cB + o + 2 * 1024 + xo1);                       \
    bf[1][0] = *(const half8*)(cB + o + 3 * 1024 + xo0);                       \
    bf[1][1] = *(const half8*)(cB + o + 3 * 1024 + xo1);                       \
    QUAD(0, 2);                                                                \
    __builtin_amdgcn_s_barrier();                                              \
    /* P3: stage (t+2).A.h1 + (t+2).B.h0; MFMA; vmcnt(6) */                    \
    STG(0, (BUF), kt2, 1);                                                     \
    STG(1, (BUF), kt2, 0);                                                     \
    QUAD(4, 2);                                                                \
    asm volatile("s_waitcnt vmcnt(6)" ::: "memory");                           \
    __builtin_amdgcn_s_barrier();                                              \
  } while (0)

  for (int tt = 0; tt < NT; tt += 2) {
    TILE(0, tt);
    TILE(1, tt + 1);
  }

  const int z = blockIdx.z;
#pragma unroll
  for (int i = 0; i < 8; i++)
#pragma unroll
    for (int j = 0; j < 4; j++) {
      const int col = n0 + wn + j * 16 + fr;
      const int rbase = m0 + wm + i * 16 + fq * 4;
      if (MODE == 0 && z == 0) {
        const float bv = bias[col];
#pragma unroll
        for (int r = 0; r < 4; r++)
          Cf[(size_t)(rbase + r) * 4096 + col] = acc[i][j][r] + bv;
      } else {
        _Float16* P = z ? H1 : H0;
#pragma unroll
        for (int r = 0; r < 4; r++)
          P[(size_t)(rbase + r) * 4096 + col] = (_Float16)acc[i][j][r];
      }
    }
#undef TILE
#undef QUAD
#undef STG
}

// ---- prepB (fused): cvt Wre (8192 blk) + combine1 (2048 blk) ----------------
// combine1: q = (p0 + p1 + bq) * 0.125, linear [m][col] -> q-attn layout.
__global__ __launch_bounds__(256) void prepB(const float* __restrict__ Wre,
                                             _Float16* __restrict__ WreH,
                                             const _Float16* __restrict__ p0,
                                             const _Float16* __restrict__ p1,
                                             const float* __restrict__ bq,
                                             _Float16* __restrict__ q) {
  const int bid = blockIdx.x, t = threadIdx.x;
  if (bid < 8192) {
    cvt8(Wre, WreH, bid * 256 + t);
    return;
  }
  __shared__ _Float16 T[4][16][80];  // row stride 160B: 16B-aligned, bank-rotating
  const int L = t & 63, w = t >> 6;
  const int m = bid - 8192, d = w;
  const int b = m >> 9, s = m & 511;
  const size_t src = (size_t)m * 4096 + d * 1024 + L * 16;
  half8 a0 = *(const half8*)(p0 + src);
  half8 a1 = *(const half8*)(p0 + src + 8);
  half8 b0 = *(const half8*)(p1 + src);
  half8 b1 = *(const half8*)(p1 + src + 8);
  const float4* bqv = (const float4*)(bq + d * 1024 + L * 16);
  float bias[16];
#pragma unroll
  for (int c = 0; c < 4; c++) {
    float4 f = bqv[c];
    bias[c * 4 + 0] = f.x; bias[c * 4 + 1] = f.y;
    bias[c * 4 + 2] = f.z; bias[c * 4 + 3] = f.w;
  }
#pragma unroll
  for (int h = 0; h < 8; h++) {
    T[w][h][L] = (_Float16)(((float)a0[h] + (float)b0[h] + bias[h]) * 0.125f);
    T[w][h + 8][L] =
        (_Float16)(((float)a1[h] + (float)b1[h] + bias[h + 8]) * 0.125f);
  }
  const int h2 = L >> 2, c2 = L & 3;
  _Float16* dst = q + (((size_t)(b * 16 + h2) * 2048) + s * 4 + d) * 64 + c2 * 8;
  *(half8*)dst = *(const half8*)&T[w][h2][c2 * 8];
  *(half8*)(dst + 32) = *(const half8*)&T[w][h2][32 + c2 * 8];
}

// ---- combine2: out[i] += (float)p1[i], in place (element-owned, race-free) --
__global__ __launch_bounds__(256) void combine2(float* __restrict__ out,
                                                const _Float16* __restrict__ p1) {
  const int i4 = (blockIdx.x * 256 + threadIdx.x) * 4;
  float4 o = *(float4*)&out[i4];
  half4 p = *(const half4*)(p1 + i4);
  o.x += (float)p[0];
  o.y += (float)p[1];
  o.z += (float)p[2];
  o.w += (float)p[3];
  *(float4*)&out[i4] = o;
}

// ---------------- MFMA flash attention --------------------------------------
// grid (16 q-tiles, 64 bh), 256 threads = 4 waves. Q-tile 128 rows, 32/wave.
// V-tile loads hoisted into registers before the exp/softmax VALU section so
// their L2 latency drains under ~400 cyc of VALU instead of stalling PV MFMAs.
__global__ __launch_bounds__(256) void attn_mfma(const _Float16* __restrict__ Q,
                                                 const _Float16* __restrict__ Kh,
                                                 const _Float16* __restrict__ Vt,
                                                 float* __restrict__ Out) {
  __shared__ _Float16 Pbuf[4][32][136];
  const int t = threadIdx.x, lane = t & 63, w = t >> 6;
  const int fr = lane & 15, fq = lane >> 4;
  const int bh = blockIdx.y, qt = blockIdx.x;
  const int b = bh >> 4, h = bh & 15;

  const _Float16* Qb = Q + ((size_t)bh * 2048 + qt * 128 + w * 32) * 64;
  const _Float16* Kb = Kh + (size_t)bh * 512 * 64;
  const _Float16* Vb = Vt + (size_t)bh * 64 * 512;

  half8 qf[2][2];
#pragma unroll
  for (int i = 0; i < 2; i++)
#pragma unroll
    for (int ks = 0; ks < 2; ks++)
      qf[i][ks] = *(const half8*)(Qb + (i * 16 + fr) * 64 + ks * 32 + fq * 8);

  floatx4 oacc[2][4];
  float l_acc[2][4];
#pragma unroll
  for (int i = 0; i < 2; i++)
#pragma unroll
    for (int j = 0; j < 4; j++) {
      oacc[i][j] = (floatx4)(0.f);
      l_acc[i][j] = 0.f;
    }

  for (int c0 = 0; c0 < 512; c0 += 128) {
    floatx4 sc[2][8];
#pragma unroll
    for (int i = 0; i < 2; i++)
#pragma unroll
      for (int j = 0; j < 8; j++) sc[i][j] = (floatx4)(0.f);
#pragma unroll
    for (int j = 0; j < 8; j++) {
      const _Float16* kr = Kb + (size_t)(c0 + j * 16 + fr) * 64 + fq * 8;
      half8 k0 = *(const half8*)kr;
      half8 k1 = *(const half8*)(kr + 32);
#pragma unroll
      for (int i = 0; i < 2; i++) {
        sc[i][j] = __builtin_amdgcn_mfma_f32_16x16x32_f16(qf[i][0], k0, sc[i][j], 0, 0, 0);
        sc[i][j] = __builtin_amdgcn_mfma_f32_16x16x32_f16(qf[i][1], k1, sc[i][j], 0, 0, 0);
      }
    }
    // ---- hoisted V loads: issue all 16 before the softmax VALU section ----
    half8 vr[4][4];
#pragma unroll
    for (int kn = 0; kn < 4; kn++)
#pragma unroll
      for (int jv = 0; jv < 4; jv++)
        vr[kn][jv] =
            *(const half8*)(Vb + (size_t)(jv * 16 + fr) * 512 + c0 + kn * 32 + fq * 8);
#pragma unroll
    for (int i = 0; i < 2; i++)
#pragma unroll
      for (int j = 0; j < 8; j++)
#pragma unroll
        for (int r = 0; r < 4; r++) {
          float p = __expf(sc[i][j][r]);
          l_acc[i][r] += p;
          Pbuf[w][i * 16 + fq * 4 + r][j * 16 + fr] = (_Float16)p;
        }
#pragma unroll
    for (int kn = 0; kn < 4; kn++) {
      half8 pa[2];
#pragma unroll
      for (int i = 0; i < 2; i++)
        pa[i] = *(const half8*)&Pbuf[w][i * 16 + fr][kn * 32 + fq * 8];
#pragma unroll
      for (int jv = 0; jv < 4; jv++) {
#pragma unroll
        for (int i = 0; i < 2; i++)
          oacc[i][jv] = __builtin_amdgcn_mfma_f32_16x16x32_f16(pa[i], vr[kn][jv],
                                                              oacc[i][jv], 0, 0, 0);
      }
    }
  }

#pragma unroll
  for (int i = 0; i < 2; i++)
#pragma unroll
    for (int r = 0; r < 4; r++) {
#pragma unroll
      for (int m = 8; m; m >>= 1)
        l_acc[i][r] += __shfl_xor(l_acc[i][r], m, 16);
    }
#pragma unroll
  for (int i = 0; i < 2; i++) {
#pragma unroll
    for (int r = 0; r < 4; r++) {
      const float inv = 1.f / l_acc[i][r];
      const int m2 = qt * 128 + w * 32 + i * 16 + fq * 4 + r;
      float* orow = Out + ((size_t)(b * 512 + (m2 >> 2))) * 4096 + h * 256 + (m2 & 3) * 64 + fr;
#pragma unroll
      for (int jv = 0; jv < 4; jv++) orow[jv * 16] = oacc[i][jv][r] * inv;
    }
  }
}

// ---------------- LayerNorm over 4096, output f16 ---------------------------
__global__ __launch_bounds__(256) void ln_kernel(const float* __restrict__ X,
                                                 const float* __restrict__ g,
                                                 const float* __restrict__ bb,
                                                 _Float16* __restrict__ Y) {
  const int row = blockIdx.x;
  const int t = threadIdx.x;
  const float* x = X + (size_t)row * 4096;
  float4 vals[4];
  float sum = 0.f, sq = 0.f;
#pragma unroll
  for (int c = 0; c < 4; c++) {
    vals[c] = *(const float4*)&x[c * 1024 + t * 4];
    sum += vals[c].x + vals[c].y + vals[c].z + vals[c].w;
    sq += vals[c].x * vals[c].x + vals[c].y * vals[c].y + vals[c].z * vals[c].z +
          vals[c].w * vals[c].w;
  }
#pragma unroll
  for (int off = 32; off > 0; off >>= 1) {
    sum += __shfl_down(sum, off, 64);
    sq += __shfl_down(sq, off, 64);
  }
  __shared__ float red[8];
  const int w = t >> 6;
  if ((t & 63) == 0) {
    red[w] = sum;
    red[4 + w] = sq;
  }
  __syncthreads();
  sum = red[0] + red[1] + red[2] + red[3];
  sq = red[4] + red[5] + red[6] + red[7];
  const float mu = sum * (1.f / 4096.f);
  float var = sq * (1.f / 4096.f) - mu * mu;
  var = fmaxf(var, 0.f);
  const float rstd = rsqrtf(var + 1e-12f);
#pragma unroll
  for (int c = 0; c < 4; c++) {
    const int j = c * 1024 + t * 4;
    float4 gg = *(const float4*)&g[j];
    float4 bv = *(const float4*)&bb[j];
    half4 y;
    y[0] = (_Float16)((vals[c].x - mu) * rstd * gg.x + bv.x);
    y[1] = (_Float16)((vals[c].y - mu) * rstd * gg.y + bv.y);
    y[2] = (_Float16)((vals[c].z - mu) * rstd * gg.z + bv.z);
    y[3] = (_Float16)((vals[c].w - mu) * rstd * gg.w + bv.w);
    *(half4*)&Y[(size_t)row * 4096 + j] = y;
  }
}

// ---------------- launcher --------------------------------------------------
extern "C" void kernel_launch(void* const* d_in, const int* in_sizes, int n_in,
                              void* d_out, int out_size, void* d_ws,
                              size_t ws_size, hipStream_t stream) {
  const float* emb = (const float*)d_in[0];
  const float* keys = (const float*)d_in[1];
  const float* values = (const float*)d_in[2];
  const float* Wq = (const float*)d_in[3];
  const float* bq = (const float*)d_in[4];
  const float* Wre = (const float*)d_in[5];
  const float* bre = (const float*)d_in[6];
  const float* ln_g = (const float*)d_in[7];
  const float* ln_b = (const float*)d_in[8];
  float* out = (float*)d_out;

  char* ws = (char*)d_ws;
  _Float16* embH = (_Float16*)(ws);
  _Float16* WqH = (_Float16*)(ws + ((size_t)16 << 20));
  _Float16* Kh = (_Float16*)(ws + ((size_t)48 << 20));
  _Float16* Vt = (_Float16*)(ws + ((size_t)52 << 20));
  _Float16* P0q = (_Float16*)d_out;
  _Float16* P1q = (_Float16*)((char*)d_out + ((size_t)16 << 20));
  _Float16* WreH = WqH;
  _Float16* qattn = (_Float16*)(ws);
  _Float16* lnH = (_Float16*)(ws + ((size_t)48 << 20));
  _Float16* P1o = (_Float16*)(ws);

  prepA<<<20480, 256, 0, stream>>>(emb, Wq, keys, values, embH, WqH, Kh, Vt);
  gemm_bt<1><<<dim3(16, 8, 2), 512, 0, stream>>>(embH, WqH, nullptr, nullptr,
                                                 P0q, P1q);
  prepB<<<10240, 256, 0, stream>>>(Wre, WreH, P0q, P1q, bq, qattn);
  attn_mfma<<<dim3(16, 64), 256, 0, stream>>>(qattn, Kh, Vt, out);
  ln_kernel<<<2048, 256, 0, stream>>>(out, ln_g, ln_b, lnH);
  gemm_bt<0><<<dim3(16, 8, 2), 512, 0, stream>>>(lnH, WreH, bre, out, nullptr,
                                                 P1o);
  combine2<<<8192, 256, 0, stream>>>(out, P1o);
}

// Round 5
// 431.392 us; speedup vs baseline: 1.0768x; 1.0288x over previous
//
#include <hip/hip_runtime.h>

typedef __attribute__((ext_vector_type(8))) _Float16 half8;
typedef __attribute__((ext_vector_type(4))) _Float16 half4;
typedef __attribute__((ext_vector_type(4))) float    floatx4;

#define GLD16(g, l)                                                            \
  __builtin_amdgcn_global_load_lds(                                            \
      (const __attribute__((address_space(1))) void*)(g),                      \
      (__attribute__((address_space(3))) void*)(l), 16, 0, 0)

#define MFMA16(a, b, c) __builtin_amdgcn_mfma_f32_16x16x32_f16(a, b, c, 0, 0, 0)

__device__ __forceinline__ void cvt8(const float* __restrict__ in,
                                     _Float16* __restrict__ out, int i) {
  const float4* p = (const float4*)in + (size_t)i * 2;
  float4 a = p[0], b = p[1];
  half8 h;
  h[0] = (_Float16)a.x; h[1] = (_Float16)a.y; h[2] = (_Float16)a.z; h[3] = (_Float16)a.w;
  h[4] = (_Float16)b.x; h[5] = (_Float16)b.y; h[6] = (_Float16)b.z; h[7] = (_Float16)b.w;
  *(half8*)(out + (size_t)i * 8) = h;
}

// ---- prepA (fused): cvt emb (4096 blk) + cvt Wq (8192 blk) + prep_kv (8192) -
__global__ __launch_bounds__(256) void prepA(const float* __restrict__ emb,
                                             const float* __restrict__ Wq,
                                             const float* __restrict__ keys,
                                             const float* __restrict__ values,
                                             _Float16* __restrict__ embH,
                                             _Float16* __restrict__ WqH,
                                             _Float16* __restrict__ Kh,
                                             _Float16* __restrict__ Vt) {
  const int bid = blockIdx.x, t = threadIdx.x;
  if (bid < 4096) {
    cvt8(emb, embH, bid * 256 + t);
  } else if (bid < 12288) {
    cvt8(Wq, WqH, (bid - 4096) * 256 + t);
  } else {
    const int tid = (bid - 12288) * 256 + t;  // < 2M
    {
      int v = tid & 63, n = (tid >> 6) & 511, h = (tid >> 15) & 15, b = tid >> 19;
      Kh[tid] = (_Float16)keys[((size_t)(b * 512 + n)) * 1024 + v * 16 + h];
    }
    {
      int n = tid & 511, v = (tid >> 9) & 63, h = (tid >> 15) & 15, b = tid >> 19;
      Vt[tid] = (_Float16)values[((size_t)(b * 512 + n)) * 1024 + v * 16 + h];
    }
  }
}

// ---------------- GEMM_BT full-K, 128x128 tile, 4-wave, 4-phase, dbuf -------
// C[m,n] = sum_k A[m,k]*B[n,k]. M=2048, N=4096, K=4096. NO split-K: grid
// 32x16 = 512 blocks = 2 blocks/CU (64 KiB LDS each), so two INDEPENDENT
// barrier-groups per CU overlap each other's sync/latency gaps — the round-0
// mechanism — on top of the in-block counted-vmcnt pipeline.
// NT=64 K-tiles of BK=64. 256 threads = 4 waves (2M x 2N), per-wave 64x64.
// LDS: lA[2][128][64] + lB[2][128][64] f16 = 64 KiB. XOR chunk swizzle
// (chunk c of row r at slot c^(r&7)) on the global SOURCE address.
// Phases (reads 8/4/4/0, MFMA 8/8/8/8, one barrier each):
//   P0: read af01+bf01 (8)            | QUAD(i0-1,j0-1) | BAR
//   P1: stage (t+2) A.h0,A.h2,B.h0,B.h2 | read af23 (4) | QUAD(i2-3,j0-1) | BAR
//   P2: stage (t+2) A.h1,A.h3           | read bf23 (4) | QUAD(i0-1,j2-3) | BAR
//   P3: stage (t+2) B.h1,B.h3           | QUAD(i2-3,j2-3) | vmcnt(8) | BAR
// Region death (wm,wn ∈ {0,64}; frag rows i*16+fr):
//   A.h0/h2 (rows 0-31,64-95) last read P0 (af01) -> stage @P1 legal;
//   A.h1/h3 last read P1 (af23) -> @P2; B.h0/h2 last read P0 (bf01) -> @P1;
//   B.h1/h3 last read P2 (bf23) -> @P3. The barrier ending each phase orders
//   death before the next phase's STG. All 8 GLD of tile t+2 are issued
//   during tile t (4/2/2); vmcnt(8) at tile end retires exactly tile t+1's 8
//   (issued during t-1), leaving t+2's 8 in flight — never vmcnt(0) in-loop.
//   Tail kt2 is clamped: rewrites the resident last tile with identical
//   bytes (benign), keeping the vmcnt count exact.
// No asm lgkmcnt/sched_barrier: frag reads are compiler-visible, hipcc emits
// fine-grained counted lgkmcnt before each consuming MFMA (m97 behavior).
// MODE 1 (gemm1): H0 f16 linear, no bias. MODE 0 (gemm2): Cf f32 + bias[col].
template <int MODE>
__global__ __launch_bounds__(256, 2) void gemm_bt(const _Float16* __restrict__ A,
                                                  const _Float16* __restrict__ Bw,
                                                  const float* __restrict__ bias,
                                                  float* __restrict__ Cf,
                                                  _Float16* __restrict__ H0) {
  const int K = 4096;
  const int NT = 64;
  __shared__ _Float16 lA[2 * 8192];
  __shared__ _Float16 lB[2 * 8192];
  const int t = threadIdx.x, lane = t & 63, w = t >> 6;
  const int m0 = blockIdx.y * 128, n0 = blockIdx.x * 128;
  const int wm = (w >> 1) * 64, wn = (w & 1) * 64;
  const int fr = lane & 15, fq = lane >> 4;

  const int srow = t >> 3;                 // 0..31 (32 rows per GLD)
  const int sch = (t & 7) ^ (srow & 7);    // swizzled source chunk
  const _Float16* gA = A + (size_t)(m0 + srow) * K + sch * 8;
  const _Float16* gB = Bw + (size_t)(n0 + srow) * K + sch * 8;
  _Float16* dA = &lA[t * 8];
  _Float16* dB = &lB[t * 8];

// one GLD: op 0=A 1=B, buffer bf_, k-tile kt_, quarter h_ (32 rows)
#define STG(op, bf_, kt_, h_)                                                  \
  GLD16((op ? gB : gA) + (size_t)((h_)*32) * K + (kt_)*64,                     \
        (op ? dB : dA) + (bf_)*8192 + (h_)*2048)

  // prologue: tile0 (8 GLD) + tile1 (8 GLD); vmcnt(8) retires tile0's 8.
  STG(0, 0, 0, 0); STG(0, 0, 0, 1); STG(0, 0, 0, 2); STG(0, 0, 0, 3);
  STG(1, 0, 0, 0); STG(1, 0, 0, 1); STG(1, 0, 0, 2); STG(1, 0, 0, 3);
  STG(0, 1, 1, 0); STG(0, 1, 1, 1); STG(0, 1, 1, 2); STG(0, 1, 1, 3);
  STG(1, 1, 1, 0); STG(1, 1, 1, 1); STG(1, 1, 1, 2); STG(1, 1, 1, 3);
  asm volatile("s_waitcnt vmcnt(8)" ::: "memory");
  __builtin_amdgcn_s_barrier();

  floatx4 acc[4][4];
#pragma unroll
  for (int i = 0; i < 4; i++)
#pragma unroll
    for (int j = 0; j < 4; j++) acc[i][j] = (floatx4)(0.f);

  // per-wave LDS read bases; XOR term is row-invariant (wm,wn,i*16 ≡ 0 mod 8)
  const _Float16* cA = lA + (wm + fr) * 64;
  const _Float16* cB = lB + (wn + fr) * 64;
  const int xo0 = ((fq) ^ (fr & 7)) * 8;
  const int xo1 = ((4 + fq) ^ (fr & 7)) * 8;

#define QUAD(ibase, jbase)                                                     \
  do {                                                                         \
    __builtin_amdgcn_s_setprio(1);                                             \
    _Pragma("unroll") for (int i_ = 0; i_ < 2; i_++) {                         \
      _Pragma("unroll") for (int jj_ = 0; jj_ < 2; jj_++) {                    \
        acc[(ibase) + i_][(jbase) + jj_] = MFMA16(                             \
            af[(ibase) + i_][0], bf[(jbase) + jj_][0],                         \
            acc[(ibase) + i_][(jbase) + jj_]);                                 \
        acc[(ibase) + i_][(jbase) + jj_] = MFMA16(                             \
            af[(ibase) + i_][1], bf[(jbase) + jj_][1],                         \
            acc[(ibase) + i_][(jbase) + jj_]);                                 \
      }                                                                        \
    }                                                                          \
    __builtin_amdgcn_s_setprio(0);                                             \
  } while (0)

#define TILE(BUF, TT)                                                          \
  do {                                                                         \
    const int kt2 = ((TT) + 2 < NT) ? (TT) + 2 : NT - 1;                       \
    const int o = (BUF)*8192;                                                  \
    half8 af[4][2], bf[4][2];                                                  \
    /* P0: read af01+bf01; MFMA(i0-1,j0-1) */                                  \
    _Pragma("unroll") for (int i = 0; i < 2; i++) {                            \
      af[i][0] = *(const half8*)(cA + o + i * 1024 + xo0);                     \
      af[i][1] = *(const half8*)(cA + o + i * 1024 + xo1);                     \
    }                                                                          \
    _Pragma("unroll") for (int j = 0; j < 2; j++) {                            \
      bf[j][0] = *(const half8*)(cB + o + j * 1024 + xo0);                     \
      bf[j][1] = *(const half8*)(cB + o + j * 1024 + xo1);                     \
    }                                                                          \
    QUAD(0, 0);                                                                \
    __builtin_amdgcn_s_barrier();                                              \
    /* P1: stage (t+2).A.h0,h2 + B.h0,h2 (dead @P0); read af23; MFMA */        \
    STG(0, (BUF), kt2, 0); STG(0, (BUF), kt2, 2);                              \
    STG(1, (BUF), kt2, 0); STG(1, (BUF), kt2, 2);                              \
    _Pragma("unroll") for (int i = 2; i < 4; i++) {                            \
      af[i][0] = *(const half8*)(cA + o + i * 1024 + xo0);                     \
      af[i][1] = *(const half8*)(cA + o + i * 1024 + xo1);                     \
    }                                                                          \
    QUAD(2, 0);                                                                \
    __builtin_amdgcn_s_barrier();                                              \
    /* P2: stage (t+2).A.h1,h3 (dead @P1); read bf23; MFMA */                  \
    STG(0, (BUF), kt2, 1); STG(0, (BUF), kt2, 3);                              \
    _Pragma("unroll") for (int j = 2; j < 4; j++) {                            \
      bf[j][0] = *(const half8*)(cB + o + j * 1024 + xo0);                     \
      bf[j][1] = *(const half8*)(cB + o + j * 1024 + xo1);                     \
    }                                                                          \
    QUAD(0, 2);                                                                \
    __builtin_amdgcn_s_barrier();                                              \
    /* P3: stage (t+2).B.h1,h3 (dead @P2); MFMA; vmcnt(8) */                   \
    STG(1, (BUF), kt2, 1); STG(1, (BUF), kt2, 3);                              \
    QUAD(2, 2);                                                                \
    asm volatile("s_waitcnt vmcnt(8)" ::: "memory");                           \
    __builtin_amdgcn_s_barrier();                                              \
  } while (0)

  for (int tt = 0; tt < NT; tt += 2) {
    TILE(0, tt);
    TILE(1, tt + 1);
  }

#pragma unroll
  for (int i = 0; i < 4; i++)
#pragma unroll
    for (int j = 0; j < 4; j++) {
      const int col = n0 + wn + j * 16 + fr;
      const int rbase = m0 + wm + i * 16 + fq * 4;
      if (MODE == 0) {
        const float bv = bias[col];
#pragma unroll
        for (int r = 0; r < 4; r++)
          Cf[(size_t)(rbase + r) * 4096 + col] = acc[i][j][r] + bv;
      } else {
#pragma unroll
        for (int r = 0; r < 4; r++)
          H0[(size_t)(rbase + r) * 4096 + col] = (_Float16)acc[i][j][r];
      }
    }
#undef TILE
#undef QUAD
#undef STG
}

// ---- prepB (fused): cvt Wre (8192 blk) + combine1 (2048 blk) ----------------
// combine1: q = (p0 + bq) * 0.125, linear [m][col] -> q-attn layout.
__global__ __launch_bounds__(256) void prepB(const float* __restrict__ Wre,
                                             _Float16* __restrict__ WreH,
                                             const _Float16* __restrict__ p0,
                                             const float* __restrict__ bq,
                                             _Float16* __restrict__ q) {
  const int bid = blockIdx.x, t = threadIdx.x;
  if (bid < 8192) {
    cvt8(Wre, WreH, bid * 256 + t);
    return;
  }
  __shared__ _Float16 T[4][16][80];  // row stride 160B: 16B-aligned, bank-rotating
  const int L = t & 63, w = t >> 6;
  const int m = bid - 8192, d = w;
  const int b = m >> 9, s = m & 511;
  const size_t src = (size_t)m * 4096 + d * 1024 + L * 16;
  half8 a0 = *(const half8*)(p0 + src);
  half8 a1 = *(const half8*)(p0 + src + 8);
  const float4* bqv = (const float4*)(bq + d * 1024 + L * 16);
  float bias[16];
#pragma unroll
  for (int c = 0; c < 4; c++) {
    float4 f = bqv[c];
    bias[c * 4 + 0] = f.x; bias[c * 4 + 1] = f.y;
    bias[c * 4 + 2] = f.z; bias[c * 4 + 3] = f.w;
  }
#pragma unroll
  for (int h = 0; h < 8; h++) {
    T[w][h][L] = (_Float16)(((float)a0[h] + bias[h]) * 0.125f);
    T[w][h + 8][L] = (_Float16)(((float)a1[h] + bias[h + 8]) * 0.125f);
  }
  const int h2 = L >> 2, c2 = L & 3;
  _Float16* dst = q + (((size_t)(b * 16 + h2) * 2048) + s * 4 + d) * 64 + c2 * 8;
  *(half8*)dst = *(const half8*)&T[w][h2][c2 * 8];
  *(half8*)(dst + 32) = *(const half8*)&T[w][h2][32 + c2 * 8];
}

// ---------------- MFMA flash attention --------------------------------------
// grid (16 q-tiles, 64 bh), 256 threads = 4 waves. Q-tile 128 rows, 32/wave.
// V-tile loads hoisted into registers before the exp/softmax VALU section so
// their L2 latency drains under ~400 cyc of VALU instead of stalling PV MFMAs.
__global__ __launch_bounds__(256) void attn_mfma(const _Float16* __restrict__ Q,
                                                 const _Float16* __restrict__ Kh,
                                                 const _Float16* __restrict__ Vt,
                                                 float* __restrict__ Out) {
  __shared__ _Float16 Pbuf[4][32][136];
  const int t = threadIdx.x, lane = t & 63, w = t >> 6;
  const int fr = lane & 15, fq = lane >> 4;
  const int bh = blockIdx.y, qt = blockIdx.x;
  const int b = bh >> 4, h = bh & 15;

  const _Float16* Qb = Q + ((size_t)bh * 2048 + qt * 128 + w * 32) * 64;
  const _Float16* Kb = Kh + (size_t)bh * 512 * 64;
  const _Float16* Vb = Vt + (size_t)bh * 64 * 512;

  half8 qf[2][2];
#pragma unroll
  for (int i = 0; i < 2; i++)
#pragma unroll
    for (int ks = 0; ks < 2; ks++)
      qf[i][ks] = *(const half8*)(Qb + (i * 16 + fr) * 64 + ks * 32 + fq * 8);

  floatx4 oacc[2][4];
  float l_acc[2][4];
#pragma unroll
  for (int i = 0; i < 2; i++)
#pragma unroll
    for (int j = 0; j < 4; j++) {
      oacc[i][j] = (floatx4)(0.f);
      l_acc[i][j] = 0.f;
    }

  for (int c0 = 0; c0 < 512; c0 += 128) {
    floatx4 sc[2][8];
#pragma unroll
    for (int i = 0; i < 2; i++)
#pragma unroll
      for (int j = 0; j < 8; j++) sc[i][j] = (floatx4)(0.f);
#pragma unroll
    for (int j = 0; j < 8; j++) {
      const _Float16* kr = Kb + (size_t)(c0 + j * 16 + fr) * 64 + fq * 8;
      half8 k0 = *(const half8*)kr;
      half8 k1 = *(const half8*)(kr + 32);
#pragma unroll
      for (int i = 0; i < 2; i++) {
        sc[i][j] = __builtin_amdgcn_mfma_f32_16x16x32_f16(qf[i][0], k0, sc[i][j], 0, 0, 0);
        sc[i][j] = __builtin_amdgcn_mfma_f32_16x16x32_f16(qf[i][1], k1, sc[i][j], 0, 0, 0);
      }
    }
    // ---- hoisted V loads: issue all 16 before the softmax VALU section ----
    half8 vr[4][4];
#pragma unroll
    for (int kn = 0; kn < 4; kn++)
#pragma unroll
      for (int jv = 0; jv < 4; jv++)
        vr[kn][jv] =
            *(const half8*)(Vb + (size_t)(jv * 16 + fr) * 512 + c0 + kn * 32 + fq * 8);
#pragma unroll
    for (int i = 0; i < 2; i++)
#pragma unroll
      for (int j = 0; j < 8; j++)
#pragma unroll
        for (int r = 0; r < 4; r++) {
          float p = __expf(sc[i][j][r]);
          l_acc[i][r] += p;
          Pbuf[w][i * 16 + fq * 4 + r][j * 16 + fr] = (_Float16)p;
        }
#pragma unroll
    for (int kn = 0; kn < 4; kn++) {
      half8 pa[2];
#pragma unroll
      for (int i = 0; i < 2; i++)
        pa[i] = *(const half8*)&Pbuf[w][i * 16 + fr][kn * 32 + fq * 8];
#pragma unroll
      for (int jv = 0; jv < 4; jv++) {
#pragma unroll
        for (int i = 0; i < 2; i++)
          oacc[i][jv] = __builtin_amdgcn_mfma_f32_16x16x32_f16(pa[i], vr[kn][jv],
                                                              oacc[i][jv], 0, 0, 0);
      }
    }
  }

#pragma unroll
  for (int i = 0; i < 2; i++)
#pragma unroll
    for (int r = 0; r < 4; r++) {
#pragma unroll
      for (int m = 8; m; m >>= 1)
        l_acc[i][r] += __shfl_xor(l_acc[i][r], m, 16);
    }
#pragma unroll
  for (int i = 0; i < 2; i++) {
#pragma unroll
    for (int r = 0; r < 4; r++) {
      const float inv = 1.f / l_acc[i][r];
      const int m2 = qt * 128 + w * 32 + i * 16 + fq * 4 + r;
      float* orow = Out + ((size_t)(b * 512 + (m2 >> 2))) * 4096 + h * 256 + (m2 & 3) * 64 + fr;
#pragma unroll
      for (int jv = 0; jv < 4; jv++) orow[jv * 16] = oacc[i][jv][r] * inv;
    }
  }
}

// ---------------- LayerNorm over 4096, output f16 ---------------------------
__global__ __launch_bounds__(256) void ln_kernel(const float* __restrict__ X,
                                                 const float* __restrict__ g,
                                                 const float* __restrict__ bb,
                                                 _Float16* __restrict__ Y) {
  const int row = blockIdx.x;
  const int t = threadIdx.x;
  const float* x = X + (size_t)row * 4096;
  float4 vals[4];
  float sum = 0.f, sq = 0.f;
#pragma unroll
  for (int c = 0; c < 4; c++) {
    vals[c] = *(const float4*)&x[c * 1024 + t * 4];
    sum += vals[c].x + vals[c].y + vals[c].z + vals[c].w;
    sq += vals[c].x * vals[c].x + vals[c].y * vals[c].y + vals[c].z * vals[c].z +
          vals[c].w * vals[c].w;
  }
#pragma unroll
  for (int off = 32; off > 0; off >>= 1) {
    sum += __shfl_down(sum, off, 64);
    sq += __shfl_down(sq, off, 64);
  }
  __shared__ float red[8];
  const int w = t >> 6;
  if ((t & 63) == 0) {
    red[w] = sum;
    red[4 + w] = sq;
  }
  __syncthreads();
  sum = red[0] + red[1] + red[2] + red[3];
  sq = red[4] + red[5] + red[6] + red[7];
  const float mu = sum * (1.f / 4096.f);
  float var = sq * (1.f / 4096.f) - mu * mu;
  var = fmaxf(var, 0.f);
  const float rstd = rsqrtf(var + 1e-12f);
#pragma unroll
  for (int c = 0; c < 4; c++) {
    const int j = c * 1024 + t * 4;
    float4 gg = *(const float4*)&g[j];
    float4 bv = *(const float4*)&bb[j];
    half4 y;
    y[0] = (_Float16)((vals[c].x - mu) * rstd * gg.x + bv.x);
    y[1] = (_Float16)((vals[c].y - mu) * rstd * gg.y + bv.y);
    y[2] = (_Float16)((vals[c].z - mu) * rstd * gg.z + bv.z);
    y[3] = (_Float16)((vals[c].w - mu) * rstd * gg.w + bv.w);
    *(half4*)&Y[(size_t)row * 4096 + j] = y;
  }
}

// ---------------- launcher --------------------------------------------------
extern "C" void kernel_launch(void* const* d_in, const int* in_sizes, int n_in,
                              void* d_out, int out_size, void* d_ws,
                              size_t ws_size, hipStream_t stream) {
  const float* emb = (const float*)d_in[0];
  const float* keys = (const float*)d_in[1];
  const float* values = (const float*)d_in[2];
  const float* Wq = (const float*)d_in[3];
  const float* bq = (const float*)d_in[4];
  const float* Wre = (const float*)d_in[5];
  const float* bre = (const float*)d_in[6];
  const float* ln_g = (const float*)d_in[7];
  const float* ln_b = (const float*)d_in[8];
  float* out = (float*)d_out;

  char* ws = (char*)d_ws;
  // ws timeline (64 MiB) + d_out (32 MiB) as scratch. No split-K partials.
  //  1. prepA: embH [0,16); WqH [16,48); Kh [48,52); Vt [52,56)
  //  2. gemm1<1>: -> H f16 = d_out[0,16M)
  //  3. prepB: WreH [16,48) (WqH dead); combine1(H) -> qattn [0,16) (embH dead)
  //  4. attn(qattn,Kh,Vt) -> d_out f32            (H dead)
  //  5. ln -> lnH [48,64)                         (Kh/Vt dead)
  //  6. gemm2<0>: f32 + bre -> d_out              (final; no combine)
  _Float16* embH = (_Float16*)(ws);
  _Float16* WqH = (_Float16*)(ws + ((size_t)16 << 20));
  _Float16* Kh = (_Float16*)(ws + ((size_t)48 << 20));
  _Float16* Vt = (_Float16*)(ws + ((size_t)52 << 20));
  _Float16* P0q = (_Float16*)d_out;
  _Float16* WreH = WqH;
  _Float16* qattn = (_Float16*)(ws);
  _Float16* lnH = (_Float16*)(ws + ((size_t)48 << 20));

  prepA<<<20480, 256, 0, stream>>>(emb, Wq, keys, values, embH, WqH, Kh, Vt);
  gemm_bt<1><<<dim3(32, 16), 256, 0, stream>>>(embH, WqH, nullptr, nullptr, P0q);
  prepB<<<10240, 256, 0, stream>>>(Wre, WreH, P0q, bq, qattn);
  attn_mfma<<<dim3(16, 64), 256, 0, stream>>>(qattn, Kh, Vt, out);
  ln_kernel<<<2048, 256, 0, stream>>>(out, ln_g, ln_b, lnH);
  gemm_bt<0><<<dim3(32, 16), 256, 0, stream>>>(lnH, WreH, bre, out, nullptr);
}

// Round 6
// 428.930 us; speedup vs baseline: 1.0830x; 1.0057x over previous
//
#include <hip/hip_runtime.h>

typedef __attribute__((ext_vector_type(8))) _Float16 half8;
typedef __attribute__((ext_vector_type(4))) _Float16 half4;
typedef __attribute__((ext_vector_type(4))) float    floatx4;

#define GLD16(g, l)                                                            \
  __builtin_amdgcn_global_load_lds(                                            \
      (const __attribute__((address_space(1))) void*)(g),                      \
      (__attribute__((address_space(3))) void*)(l), 16, 0, 0)

#define MFMA16(a, b, c) __builtin_amdgcn_mfma_f32_16x16x32_f16(a, b, c, 0, 0, 0)

__device__ __forceinline__ void cvt8(const float* __restrict__ in,
                                     _Float16* __restrict__ out, int i) {
  const float4* p = (const float4*)in + (size_t)i * 2;
  float4 a = p[0], b = p[1];
  half8 h;
  h[0] = (_Float16)a.x; h[1] = (_Float16)a.y; h[2] = (_Float16)a.z; h[3] = (_Float16)a.w;
  h[4] = (_Float16)b.x; h[5] = (_Float16)b.y; h[6] = (_Float16)b.z; h[7] = (_Float16)b.w;
  *(half8*)(out + (size_t)i * 8) = h;
}

// ---- prepA (fused): cvt emb (4096 blk) + cvt Wq (8192 blk) + prep_kv (8192) -
__global__ __launch_bounds__(256) void prepA(const float* __restrict__ emb,
                                             const float* __restrict__ Wq,
                                             const float* __restrict__ keys,
                                             const float* __restrict__ values,
                                             _Float16* __restrict__ embH,
                                             _Float16* __restrict__ WqH,
                                             _Float16* __restrict__ Kh,
                                             _Float16* __restrict__ Vt) {
  const int bid = blockIdx.x, t = threadIdx.x;
  if (bid < 4096) {
    cvt8(emb, embH, bid * 256 + t);
  } else if (bid < 12288) {
    cvt8(Wq, WqH, (bid - 4096) * 256 + t);
  } else {
    const int tid = (bid - 12288) * 256 + t;  // < 2M
    {
      int v = tid & 63, n = (tid >> 6) & 511, h = (tid >> 15) & 15, b = tid >> 19;
      Kh[tid] = (_Float16)keys[((size_t)(b * 512 + n)) * 1024 + v * 16 + h];
    }
    {
      int n = tid & 511, v = (tid >> 9) & 63, h = (tid >> 15) & 15, b = tid >> 19;
      Vt[tid] = (_Float16)values[((size_t)(b * 512 + n)) * 1024 + v * 16 + h];
    }
  }
}

// ---------------- GEMM_BT full-K, 128x128 tile, 4-wave, 4-phase, dbuf -------
// C[m,n] = sum_k A[m,k]*B[n,k]. M=2048, N=4096, K=4096. NO split-K: grid
// 32x16 = 512 blocks = 2 blocks/CU (64 KiB LDS each). Two independent
// barrier-groups per CU anti-phase: one block's read-epoch overlaps the
// other's MFMA-epoch.
// NT=64 K-tiles of BK=64. 256 threads = 4 waves (2M x 2N), per-wave 64x64.
// LDS: lA[2][128][64] + lB[2][128][64] f16 = 64 KiB. XOR chunk swizzle
// (chunk c of row r at slot c^(r&7)) on the global SOURCE address.
// m201-EXACT phase structure (two barriers/phase, NO sched_barrier):
//   phase = { ds-reads | STG | BAR | s_waitcnt lgkmcnt(0) | setprio(1)
//             MFMA cluster setprio(0) | BAR }
// This forces CU-wide alternation of dense read-epochs and dense MFMA-epochs:
// every MFMA cluster starts with ALL operands resident (no mid-cluster lgkm
// stalls that starve the matrix pipe when only 1-2 waves/SIMD are resident).
// Reads 8/4/4/0, MFMA 8/8/8/8, stages 0/4/2/2 per phase:
//   P0: read af01+bf01 (8)                      | BAR lgkm0 QUAD(i0-1,j0-1) BAR
//   P1: STG (t+2) A.h0,A.h2,B.h0,B.h2 | read af23 | BAR lgkm0 QUAD(i2-3,j0-1) BAR
//   P2: STG (t+2) A.h1,A.h3           | read bf23 | BAR lgkm0 QUAD(i0-1,j2-3) BAR
//   P3: STG (t+2) B.h1,B.h3                      | BAR QUAD(i2-3,j2-3)
//       vmcnt(8) BAR
// Region death: quarters A.h0/h2,B.h0/h2 fully read at P0's lgkm0 (ordered
// before P1's STG by P0's exit barrier); A.h1/h3 at P1; B.h1/h3 at P2. All 8
// GLD of tile t+2 are issued during tile t; vmcnt(8) at tile end retires
// exactly tile t+1's 8 (issued during t-1), leaving t+2's 8 in flight —
// never vmcnt(0) in-loop. Tail kt2 clamped (byte-identical rewrites keep the
// vmcnt count exact).
// MODE 1 (gemm1): H0 f16 linear, no bias. MODE 0 (gemm2): Cf f32 + bias[col].
template <int MODE>
__global__ __launch_bounds__(256, 2) void gemm_bt(const _Float16* __restrict__ A,
                                                  const _Float16* __restrict__ Bw,
                                                  const float* __restrict__ bias,
                                                  float* __restrict__ Cf,
                                                  _Float16* __restrict__ H0) {
  const int K = 4096;
  const int NT = 64;
  __shared__ _Float16 lA[2 * 8192];
  __shared__ _Float16 lB[2 * 8192];
  const int t = threadIdx.x, lane = t & 63, w = t >> 6;
  const int m0 = blockIdx.y * 128, n0 = blockIdx.x * 128;
  const int wm = (w >> 1) * 64, wn = (w & 1) * 64;
  const int fr = lane & 15, fq = lane >> 4;

  const int srow = t >> 3;                 // 0..31 (32 rows per GLD)
  const int sch = (t & 7) ^ (srow & 7);    // swizzled source chunk
  const _Float16* gA = A + (size_t)(m0 + srow) * K + sch * 8;
  const _Float16* gB = Bw + (size_t)(n0 + srow) * K + sch * 8;
  _Float16* dA = &lA[t * 8];
  _Float16* dB = &lB[t * 8];

// one GLD: op 0=A 1=B, buffer bf_, k-tile kt_, quarter h_ (32 rows)
#define STG(op, bf_, kt_, h_)                                                  \
  GLD16((op ? gB : gA) + (size_t)((h_)*32) * K + (kt_)*64,                     \
        (op ? dB : dA) + (bf_)*8192 + (h_)*2048)

  // prologue: tile0 (8 GLD) + tile1 (8 GLD); vmcnt(8) retires tile0's 8.
  STG(0, 0, 0, 0); STG(0, 0, 0, 1); STG(0, 0, 0, 2); STG(0, 0, 0, 3);
  STG(1, 0, 0, 0); STG(1, 0, 0, 1); STG(1, 0, 0, 2); STG(1, 0, 0, 3);
  STG(0, 1, 1, 0); STG(0, 1, 1, 1); STG(0, 1, 1, 2); STG(0, 1, 1, 3);
  STG(1, 1, 1, 0); STG(1, 1, 1, 1); STG(1, 1, 1, 2); STG(1, 1, 1, 3);
  asm volatile("s_waitcnt vmcnt(8)" ::: "memory");
  __builtin_amdgcn_s_barrier();

  floatx4 acc[4][4];
#pragma unroll
  for (int i = 0; i < 4; i++)
#pragma unroll
    for (int j = 0; j < 4; j++) acc[i][j] = (floatx4)(0.f);

  // per-wave LDS read bases; XOR term is row-invariant (wm,wn,i*16 ≡ 0 mod 8)
  const _Float16* cA = lA + (wm + fr) * 64;
  const _Float16* cB = lB + (wn + fr) * 64;
  const int xo0 = ((fq) ^ (fr & 7)) * 8;
  const int xo1 = ((4 + fq) ^ (fr & 7)) * 8;

#define QUAD(ibase, jbase)                                                     \
  do {                                                                         \
    __builtin_amdgcn_s_setprio(1);                                             \
    _Pragma("unroll") for (int i_ = 0; i_ < 2; i_++) {                         \
      _Pragma("unroll") for (int jj_ = 0; jj_ < 2; jj_++) {                    \
        acc[(ibase) + i_][(jbase) + jj_] = MFMA16(                             \
            af[(ibase) + i_][0], bf[(jbase) + jj_][0],                         \
            acc[(ibase) + i_][(jbase) + jj_]);                                 \
        acc[(ibase) + i_][(jbase) + jj_] = MFMA16(                             \
            af[(ibase) + i_][1], bf[(jbase) + jj_][1],                         \
            acc[(ibase) + i_][(jbase) + jj_]);                                 \
      }                                                                        \
    }                                                                          \
    __builtin_amdgcn_s_setprio(0);                                             \
  } while (0)

#define TILE(BUF, TT)                                                          \
  do {                                                                         \
    const int kt2 = ((TT) + 2 < NT) ? (TT) + 2 : NT - 1;                       \
    const int o = (BUF)*8192;                                                  \
    half8 af[4][2], bf[4][2];                                                  \
    /* P0: read af01+bf01 | BAR lgkm0 MFMA BAR */                              \
    _Pragma("unroll") for (int i = 0; i < 2; i++) {                            \
      af[i][0] = *(const half8*)(cA + o + i * 1024 + xo0);                     \
      af[i][1] = *(const half8*)(cA + o + i * 1024 + xo1);                     \
    }                                                                          \
    _Pragma("unroll") for (int j = 0; j < 2; j++) {                            \
      bf[j][0] = *(const half8*)(cB + o + j * 1024 + xo0);                     \
      bf[j][1] = *(const half8*)(cB + o + j * 1024 + xo1);                     \
    }                                                                          \
    __builtin_amdgcn_s_barrier();                                              \
    asm volatile("s_waitcnt lgkmcnt(0)" ::: "memory");                         \
    QUAD(0, 0);                                                                \
    __builtin_amdgcn_s_barrier();                                              \
    /* P1: STG (t+2).A.h0,h2 + B.h0,h2 (dead @P0) | read af23 | BAR lgkm0 MFMA BAR */ \
    STG(0, (BUF), kt2, 0); STG(0, (BUF), kt2, 2);                              \
    STG(1, (BUF), kt2, 0); STG(1, (BUF), kt2, 2);                              \
    _Pragma("unroll") for (int i = 2; i < 4; i++) {                            \
      af[i][0] = *(const half8*)(cA + o + i * 1024 + xo0);                     \
      af[i][1] = *(const half8*)(cA + o + i * 1024 + xo1);                     \
    }                                                                          \
    __builtin_amdgcn_s_barrier();                                              \
    asm volatile("s_waitcnt lgkmcnt(0)" ::: "memory");                         \
    QUAD(2, 0);                                                                \
    __builtin_amdgcn_s_barrier();                                              \
    /* P2: STG (t+2).A.h1,h3 (dead @P1) | read bf23 | BAR lgkm0 MFMA BAR */    \
    STG(0, (BUF), kt2, 1); STG(0, (BUF), kt2, 3);                              \
    _Pragma("unroll") for (int j = 2; j < 4; j++) {                            \
      bf[j][0] = *(const half8*)(cB + o + j * 1024 + xo0);                     \
      bf[j][1] = *(const half8*)(cB + o + j * 1024 + xo1);                     \
    }                                                                          \
    __builtin_amdgcn_s_barrier();                                              \
    asm volatile("s_waitcnt lgkmcnt(0)" ::: "memory");                         \
    QUAD(0, 2);                                                                \
    __builtin_amdgcn_s_barrier();                                              \
    /* P3: STG (t+2).B.h1,h3 (dead @P2) | BAR MFMA vmcnt(8) BAR */             \
    STG(1, (BUF), kt2, 1); STG(1, (BUF), kt2, 3);                              \
    __builtin_amdgcn_s_barrier();                                              \
    QUAD(2, 2);                                                                \
    asm volatile("s_waitcnt vmcnt(8)" ::: "memory");                           \
    __builtin_amdgcn_s_barrier();                                              \
  } while (0)

  for (int tt = 0; tt < NT; tt += 2) {
    TILE(0, tt);
    TILE(1, tt + 1);
  }

#pragma unroll
  for (int i = 0; i < 4; i++)
#pragma unroll
    for (int j = 0; j < 4; j++) {
      const int col = n0 + wn + j * 16 + fr;
      const int rbase = m0 + wm + i * 16 + fq * 4;
      if (MODE == 0) {
        const float bv = bias[col];
#pragma unroll
        for (int r = 0; r < 4; r++)
          Cf[(size_t)(rbase + r) * 4096 + col] = acc[i][j][r] + bv;
      } else {
#pragma unroll
        for (int r = 0; r < 4; r++)
          H0[(size_t)(rbase + r) * 4096 + col] = (_Float16)acc[i][j][r];
      }
    }
#undef TILE
#undef QUAD
#undef STG
}

// ---- prepB (fused): cvt Wre (8192 blk) + combine1 (2048 blk) ----------------
// combine1: q = (p0 + bq) * 0.125, linear [m][col] -> q-attn layout.
__global__ __launch_bounds__(256) void prepB(const float* __restrict__ Wre,
                                             _Float16* __restrict__ WreH,
                                             const _Float16* __restrict__ p0,
                                             const float* __restrict__ bq,
                                             _Float16* __restrict__ q) {
  const int bid = blockIdx.x, t = threadIdx.x;
  if (bid < 8192) {
    cvt8(Wre, WreH, bid * 256 + t);
    return;
  }
  __shared__ _Float16 T[4][16][80];  // row stride 160B: 16B-aligned, bank-rotating
  const int L = t & 63, w = t >> 6;
  const int m = bid - 8192, d = w;
  const int b = m >> 9, s = m & 511;
  const size_t src = (size_t)m * 4096 + d * 1024 + L * 16;
  half8 a0 = *(const half8*)(p0 + src);
  half8 a1 = *(const half8*)(p0 + src + 8);
  const float4* bqv = (const float4*)(bq + d * 1024 + L * 16);
  float bias[16];
#pragma unroll
  for (int c = 0; c < 4; c++) {
    float4 f = bqv[c];
    bias[c * 4 + 0] = f.x; bias[c * 4 + 1] = f.y;
    bias[c * 4 + 2] = f.z; bias[c * 4 + 3] = f.w;
  }
#pragma unroll
  for (int h = 0; h < 8; h++) {
    T[w][h][L] = (_Float16)(((float)a0[h] + bias[h]) * 0.125f);
    T[w][h + 8][L] = (_Float16)(((float)a1[h] + bias[h + 8]) * 0.125f);
  }
  const int h2 = L >> 2, c2 = L & 3;
  _Float16* dst = q + (((size_t)(b * 16 + h2) * 2048) + s * 4 + d) * 64 + c2 * 8;
  *(half8*)dst = *(const half8*)&T[w][h2][c2 * 8];
  *(half8*)(dst + 32) = *(const half8*)&T[w][h2][32 + c2 * 8];
}

// ---------------- MFMA flash attention --------------------------------------
// grid (16 q-tiles, 64 bh), 256 threads = 4 waves. Q-tile 128 rows, 32/wave.
// V-tile loads hoisted into registers before the exp/softmax VALU section so
// their L2 latency drains under ~400 cyc of VALU instead of stalling PV MFMAs.
__global__ __launch_bounds__(256) void attn_mfma(const _Float16* __restrict__ Q,
                                                 const _Float16* __restrict__ Kh,
                                                 const _Float16* __restrict__ Vt,
                                                 float* __restrict__ Out) {
  __shared__ _Float16 Pbuf[4][32][136];
  const int t = threadIdx.x, lane = t & 63, w = t >> 6;
  const int fr = lane & 15, fq = lane >> 4;
  const int bh = blockIdx.y, qt = blockIdx.x;
  const int b = bh >> 4, h = bh & 15;

  const _Float16* Qb = Q + ((size_t)bh * 2048 + qt * 128 + w * 32) * 64;
  const _Float16* Kb = Kh + (size_t)bh * 512 * 64;
  const _Float16* Vb = Vt + (size_t)bh * 64 * 512;

  half8 qf[2][2];
#pragma unroll
  for (int i = 0; i < 2; i++)
#pragma unroll
    for (int ks = 0; ks < 2; ks++)
      qf[i][ks] = *(const half8*)(Qb + (i * 16 + fr) * 64 + ks * 32 + fq * 8);

  floatx4 oacc[2][4];
  float l_acc[2][4];
#pragma unroll
  for (int i = 0; i < 2; i++)
#pragma unroll
    for (int j = 0; j < 4; j++) {
      oacc[i][j] = (floatx4)(0.f);
      l_acc[i][j] = 0.f;
    }

  for (int c0 = 0; c0 < 512; c0 += 128) {
    floatx4 sc[2][8];
#pragma unroll
    for (int i = 0; i < 2; i++)
#pragma unroll
      for (int j = 0; j < 8; j++) sc[i][j] = (floatx4)(0.f);
#pragma unroll
    for (int j = 0; j < 8; j++) {
      const _Float16* kr = Kb + (size_t)(c0 + j * 16 + fr) * 64 + fq * 8;
      half8 k0 = *(const half8*)kr;
      half8 k1 = *(const half8*)(kr + 32);
#pragma unroll
      for (int i = 0; i < 2; i++) {
        sc[i][j] = __builtin_amdgcn_mfma_f32_16x16x32_f16(qf[i][0], k0, sc[i][j], 0, 0, 0);
        sc[i][j] = __builtin_amdgcn_mfma_f32_16x16x32_f16(qf[i][1], k1, sc[i][j], 0, 0, 0);
      }
    }
    // ---- hoisted V loads: issue all 16 before the softmax VALU section ----
    half8 vr[4][4];
#pragma unroll
    for (int kn = 0; kn < 4; kn++)
#pragma unroll
      for (int jv = 0; jv < 4; jv++)
        vr[kn][jv] =
            *(const half8*)(Vb + (size_t)(jv * 16 + fr) * 512 + c0 + kn * 32 + fq * 8);
#pragma unroll
    for (int i = 0; i < 2; i++)
#pragma unroll
      for (int j = 0; j < 8; j++)
#pragma unroll
        for (int r = 0; r < 4; r++) {
          float p = __expf(sc[i][j][r]);
          l_acc[i][r] += p;
          Pbuf[w][i * 16 + fq * 4 + r][j * 16 + fr] = (_Float16)p;
        }
#pragma unroll
    for (int kn = 0; kn < 4; kn++) {
      half8 pa[2];
#pragma unroll
      for (int i = 0; i < 2; i++)
        pa[i] = *(const half8*)&Pbuf[w][i * 16 + fr][kn * 32 + fq * 8];
#pragma unroll
      for (int jv = 0; jv < 4; jv++) {
#pragma unroll
        for (int i = 0; i < 2; i++)
          oacc[i][jv] = __builtin_amdgcn_mfma_f32_16x16x32_f16(pa[i], vr[kn][jv],
                                                              oacc[i][jv], 0, 0, 0);
      }
    }
  }

#pragma unroll
  for (int i = 0; i < 2; i++)
#pragma unroll
    for (int r = 0; r < 4; r++) {
#pragma unroll
      for (int m = 8; m; m >>= 1)
        l_acc[i][r] += __shfl_xor(l_acc[i][r], m, 16);
    }
#pragma unroll
  for (int i = 0; i < 2; i++) {
#pragma unroll
    for (int r = 0; r < 4; r++) {
      const float inv = 1.f / l_acc[i][r];
      const int m2 = qt * 128 + w * 32 + i * 16 + fq * 4 + r;
      float* orow = Out + ((size_t)(b * 512 + (m2 >> 2))) * 4096 + h * 256 + (m2 & 3) * 64 + fr;
#pragma unroll
      for (int jv = 0; jv < 4; jv++) orow[jv * 16] = oacc[i][jv][r] * inv;
    }
  }
}

// ---------------- LayerNorm over 4096, output f16 ---------------------------
__global__ __launch_bounds__(256) void ln_kernel(const float* __restrict__ X,
                                                 const float* __restrict__ g,
                                                 const float* __restrict__ bb,
                                                 _Float16* __restrict__ Y) {
  const int row = blockIdx.x;
  const int t = threadIdx.x;
  const float* x = X + (size_t)row * 4096;
  float4 vals[4];
  float sum = 0.f, sq = 0.f;
#pragma unroll
  for (int c = 0; c < 4; c++) {
    vals[c] = *(const float4*)&x[c * 1024 + t * 4];
    sum += vals[c].x + vals[c].y + vals[c].z + vals[c].w;
    sq += vals[c].x * vals[c].x + vals[c].y * vals[c].y + vals[c].z * vals[c].z +
          vals[c].w * vals[c].w;
  }
#pragma unroll
  for (int off = 32; off > 0; off >>= 1) {
    sum += __shfl_down(sum, off, 64);
    sq += __shfl_down(sq, off, 64);
  }
  __shared__ float red[8];
  const int w = t >> 6;
  if ((t & 63) == 0) {
    red[w] = sum;
    red[4 + w] = sq;
  }
  __syncthreads();
  sum = red[0] + red[1] + red[2] + red[3];
  sq = red[4] + red[5] + red[6] + red[7];
  const float mu = sum * (1.f / 4096.f);
  float var = sq * (1.f / 4096.f) - mu * mu;
  var = fmaxf(var, 0.f);
  const float rstd = rsqrtf(var + 1e-12f);
#pragma unroll
  for (int c = 0; c < 4; c++) {
    const int j = c * 1024 + t * 4;
    float4 gg = *(const float4*)&g[j];
    float4 bv = *(const float4*)&bb[j];
    half4 y;
    y[0] = (_Float16)((vals[c].x - mu) * rstd * gg.x + bv.x);
    y[1] = (_Float16)((vals[c].y - mu) * rstd * gg.y + bv.y);
    y[2] = (_Float16)((vals[c].z - mu) * rstd * gg.z + bv.z);
    y[3] = (_Float16)((vals[c].w - mu) * rstd * gg.w + bv.w);
    *(half4*)&Y[(size_t)row * 4096 + j] = y;
  }
}

// ---------------- launcher --------------------------------------------------
extern "C" void kernel_launch(void* const* d_in, const int* in_sizes, int n_in,
                              void* d_out, int out_size, void* d_ws,
                              size_t ws_size, hipStream_t stream) {
  const float* emb = (const float*)d_in[0];
  const float* keys = (const float*)d_in[1];
  const float* values = (const float*)d_in[2];
  const float* Wq = (const float*)d_in[3];
  const float* bq = (const float*)d_in[4];
  const float* Wre = (const float*)d_in[5];
  const float* bre = (const float*)d_in[6];
  const float* ln_g = (const float*)d_in[7];
  const float* ln_b = (const float*)d_in[8];
  float* out = (float*)d_out;

  char* ws = (char*)d_ws;
  // ws timeline (64 MiB) + d_out (32 MiB) as scratch. No split-K partials.
  //  1. prepA: embH [0,16); WqH [16,48); Kh [48,52); Vt [52,56)
  //  2. gemm1<1>: -> H f16 = d_out[0,16M)
  //  3. prepB: WreH [16,48) (WqH dead); combine1(H) -> qattn [0,16) (embH dead)
  //  4. attn(qattn,Kh,Vt) -> d_out f32            (H dead)
  //  5. ln -> lnH [48,64)                         (Kh/Vt dead)
  //  6. gemm2<0>: f32 + bre -> d_out              (final; no combine)
  _Float16* embH = (_Float16*)(ws);
  _Float16* WqH = (_Float16*)(ws + ((size_t)16 << 20));
  _Float16* Kh = (_Float16*)(ws + ((size_t)48 << 20));
  _Float16* Vt = (_Float16*)(ws + ((size_t)52 << 20));
  _Float16* P0q = (_Float16*)d_out;
  _Float16* WreH = WqH;
  _Float16* qattn = (_Float16*)(ws);
  _Float16* lnH = (_Float16*)(ws + ((size_t)48 << 20));

  prepA<<<20480, 256, 0, stream>>>(emb, Wq, keys, values, embH, WqH, Kh, Vt);
  gemm_bt<1><<<dim3(32, 16), 256, 0, stream>>>(embH, WqH, nullptr, nullptr, P0q);
  prepB<<<10240, 256, 0, stream>>>(Wre, WreH, P0q, bq, qattn);
  attn_mfma<<<dim3(16, 64), 256, 0, stream>>>(qattn, Kh, Vt, out);
  ln_kernel<<<2048, 256, 0, stream>>>(out, ln_g, ln_b, lnH);
  gemm_bt<0><<<dim3(32, 16), 256, 0, stream>>>(lnH, WreH, bre, out, nullptr);
}